// Round 8
// baseline (237.386 us; speedup 1.0000x reference)
//
#include <hip/hip_runtime.h>

// head u32 words: 0:c0 1:c123  (mask dtype sniff counters)
// FULL (mode 2): binplace packs u64 (local<<56)|(src<<32)|(msk<<24)|e ; finesort -> opay u64;
//   lo rows 4-bit plane xq4 (N*32 B), hi rows int8 xq8 (N*64 B).
// COMPAT (mode 1): u32 cbuf/order, xq8 for all rows, aggr gathers src/msk.
// RAW (mode 0): u32 cbuf/order, aggr quantizes from x on the fly.
// Scales are never staged: every consumer block reduces the 256-slot amax
// arrays itself (deterministic, identical in all blocks).
// Constraints: E < 2^24, N < 2^24, bsh <= 8.

#define BP_CHUNK 4096
#define FS_CAP 2560

__global__ void k_zero(unsigned* p, int n) {
  int i = blockIdx.x * blockDim.x + threadIdx.x;
  for (; i < n; i += gridDim.x * blockDim.x) p[i] = 0u;
}

// Sniff mask dtype from raw bytes (reads only N bytes, safe for u8/i32/f32).
__global__ void k_detect(const unsigned char* m, unsigned* head, int nbytes) {
  int i = blockIdx.x * blockDim.x + threadIdx.x;
  int c0 = 0, c123 = 0;
  for (; i < nbytes; i += gridDim.x * blockDim.x) {
    unsigned char b = m[i];
    if (b) { if ((i & 3) == 0) c0++; else c123++; }
  }
  for (int o = 32; o; o >>= 1) { c0 += __shfl_xor(c0, o); c123 += __shfl_xor(c123, o); }
  if ((threadIdx.x & 63) == 0) {
    if (c0)   atomicAdd(&head[0], (unsigned)c0);
    if (c123) atomicAdd(&head[1], (unsigned)c123);
  }
}

// Canonicalize mask to u8 (thread per node) + rowmax (wave per node).
__global__ void k_rowmax_canon(const float* x, const void* mraw, const unsigned* head,
                               float* rowmax, unsigned char* msk, int N) {
  int gid = blockIdx.x * blockDim.x + threadIdx.x;
  if (gid < N) {
    unsigned c0 = head[0], c123 = head[1];
    int mode = (c123 == 0u) ? 1 : ((c0 == 0u) ? 2 : 0);
    unsigned char v;
    if (mode == 0)      v = (((const unsigned char*)mraw)[gid] != 0);
    else if (mode == 1) v = (((const int*)mraw)[gid] != 0);
    else                v = (((const float*)mraw)[gid] != 0.0f);
    msk[gid] = v;
  }
  int w = gid >> 6;
  int lane = threadIdx.x & 63;
  if (w >= N) return;
  float v = fabsf(x[(size_t)w * 64 + lane]);
  for (int o = 32; o; o >>= 1) v = fmaxf(v, __shfl_xor(v, o));
  if (lane == 0) rowmax[w] = v;
}

// Wave-level reduce of two 256-slot amax arrays -> (scale_hi, scale_lo).
// All 64 lanes participate; result identical in every wave/block.
__device__ __forceinline__ void slot_scales(const unsigned* shi, const unsigned* slo,
                                            int lane, float qhi, float qlo,
                                            float& schi, float& sclo) {
  unsigned mh = shi[lane];
  unsigned ml = slo[lane];
  #pragma unroll
  for (int j = 1; j < 4; j++) {
    unsigned a = shi[lane + j * 64]; mh = mh > a ? mh : a;
    unsigned b = slo[lane + j * 64]; ml = ml > b ? ml : b;
  }
  for (int o = 32; o; o >>= 1) {
    unsigned a = __shfl_xor(mh, o); mh = mh > a ? mh : a;
    unsigned b = __shfl_xor(ml, o); ml = ml > b ? ml : b;
  }
  schi = __fdiv_rn(fmaxf(__uint_as_float(mh), 1e-8f), qhi);
  sclo = __fdiv_rn(fmaxf(__uint_as_float(ml), 1e-8f), qlo);
}

// Coarse histogram of dst>>bsh in LDS (vec4 reads), one global flush per block.
__global__ void k_edge_hist(const int* dst, unsigned* ccnt, int E, int NB, int bsh, int vec) {
  __shared__ unsigned h[1024];
  for (int i = threadIdx.x; i < NB; i += 256) h[i] = 0u;
  __syncthreads();
  int tid = blockIdx.x * blockDim.x + threadIdx.x;
  int st = gridDim.x * blockDim.x;
  int E4 = vec ? (E >> 2) : 0;
  const int4* d4 = (const int4*)dst;
  for (int i = tid; i < E4; i += st) {
    int4 v = d4[i];
    atomicAdd(&h[((unsigned)v.x) >> bsh], 1u);
    atomicAdd(&h[((unsigned)v.y) >> bsh], 1u);
    atomicAdd(&h[((unsigned)v.z) >> bsh], 1u);
    atomicAdd(&h[((unsigned)v.w) >> bsh], 1u);
  }
  for (int e = E4 * 4 + tid; e < E; e += st)
    atomicAdd(&h[((unsigned)dst[e]) >> bsh], 1u);
  __syncthreads();
  for (int i = threadIdx.x; i < NB; i += 256)
    if (h[i]) atomicAdd(&ccnt[i], h[i]);
}

// One-block exclusive scan of ccnt[NB] -> cstart[NB+1]; also init bwrite=cstart.
__global__ void k_cscan(const unsigned* ccnt, unsigned* cstart, unsigned* bwrite, int NB) {
  __shared__ unsigned sh[1024];
  int t = threadIdx.x;
  for (int i = t; i < 1024; i += 256) sh[i] = (i < NB) ? ccnt[i] : 0u;
  __syncthreads();
  for (int off = 1; off < 1024; off <<= 1) {
    unsigned v[4];
    #pragma unroll
    for (int j = 0; j < 4; j++) { int i = t + j * 256; v[j] = (i >= off) ? sh[i - off] : 0u; }
    __syncthreads();
    #pragma unroll
    for (int j = 0; j < 4; j++) { int i = t + j * 256; sh[i] += v[j]; }
    __syncthreads();
  }
  for (int i = t; i < 1024; i += 256) {
    unsigned excl = (i == 0) ? 0u : sh[i - 1];
    if (i < NB) { cstart[i] = excl; bwrite[i] = excl; }
    if (i == NB - 1) cstart[NB] = sh[i];
  }
}

// Coarse binning: LDS hist -> bulk reservation -> scatter (u64 in FULL mode,
// carrying src+msk so aggregation never re-gathers them). Also per-edge class
// amax of rowmax[src] into spread slots.
__global__ void k_binplace(const int* src, const int* dst, const unsigned char* msk,
                           const float* rowmax, unsigned* bwrite,
                           unsigned long long* cbuf64, unsigned* cbuf32,
                           unsigned* slot_ehi, unsigned* slot_elo,
                           int E, int NB, int bsh, int full, int vec) {
  __shared__ unsigned h[1024], base[1024];
  __shared__ float sh_hi[4], sh_lo[4];
  int cbase = blockIdx.x * BP_CHUNK;
  int cend = cbase + BP_CHUNK; if (cend > E) cend = E;
  int n = cend - cbase;
  int n4 = vec ? (n >> 2) : 0;
  for (int i = threadIdx.x; i < NB; i += 256) h[i] = 0u;
  __syncthreads();
  const int4* d4 = (const int4*)(dst + cbase);
  const int4* s4 = (const int4*)(src + cbase);
  for (int i = threadIdx.x; i < n4; i += 256) {
    int4 v = d4[i];
    atomicAdd(&h[((unsigned)v.x) >> bsh], 1u);
    atomicAdd(&h[((unsigned)v.y) >> bsh], 1u);
    atomicAdd(&h[((unsigned)v.z) >> bsh], 1u);
    atomicAdd(&h[((unsigned)v.w) >> bsh], 1u);
  }
  for (int e = cbase + n4 * 4 + threadIdx.x; e < cend; e += 256)
    atomicAdd(&h[((unsigned)dst[e]) >> bsh], 1u);
  __syncthreads();
  for (int i = threadIdx.x; i < NB; i += 256) {
    unsigned c = h[i];
    base[i] = c ? atomicAdd(&bwrite[i], c) : 0u;
    h[i] = 0u;  // reuse as cursor
  }
  __syncthreads();
  unsigned lmask = (1u << bsh) - 1u;
  float hi = 0.0f, lo = 0.0f;
  for (int i = threadIdx.x; i < n4; i += 256) {
    int4 dv = d4[i]; int4 sv = s4[i];
    int e0 = cbase + i * 4;
    int dd[4] = {dv.x, dv.y, dv.z, dv.w};
    int ss[4] = {sv.x, sv.y, sv.z, sv.w};
    #pragma unroll
    for (int j = 0; j < 4; j++) {
      int d = dd[j], s = ss[j];
      unsigned mk = msk[s];
      float r = rowmax[s];
      if (mk) hi = fmaxf(hi, r); else lo = fmaxf(lo, r);
      unsigned b = (unsigned)d >> bsh;
      unsigned pos = base[b] + atomicAdd(&h[b], 1u);
      if (full)
        cbuf64[pos] = ((unsigned long long)(((((unsigned)d) & lmask) << 24) | (unsigned)s) << 32)
                      | ((mk << 24) | (unsigned)(e0 + j));
      else
        cbuf32[pos] = ((((unsigned)d) & lmask) << 24) | (unsigned)(e0 + j);
    }
  }
  for (int e = cbase + n4 * 4 + threadIdx.x; e < cend; e += 256) {
    int d = dst[e], s = src[e];
    unsigned mk = msk[s];
    float r = rowmax[s];
    if (mk) hi = fmaxf(hi, r); else lo = fmaxf(lo, r);
    unsigned b = (unsigned)d >> bsh;
    unsigned pos = base[b] + atomicAdd(&h[b], 1u);
    if (full)
      cbuf64[pos] = ((unsigned long long)(((((unsigned)d) & lmask) << 24) | (unsigned)s) << 32)
                    | ((mk << 24) | (unsigned)e);
    else
      cbuf32[pos] = ((((unsigned)d) & lmask) << 24) | (unsigned)e;
  }
  for (int o = 32; o; o >>= 1) { hi = fmaxf(hi, __shfl_xor(hi, o)); lo = fmaxf(lo, __shfl_xor(lo, o)); }
  int wid = threadIdx.x >> 6, lane = threadIdx.x & 63;
  if (lane == 0) { sh_hi[wid] = hi; sh_lo[wid] = lo; }
  __syncthreads();
  if (threadIdx.x == 0) {
    float hh = fmaxf(fmaxf(sh_hi[0], sh_hi[1]), fmaxf(sh_hi[2], sh_hi[3]));
    float ll = fmaxf(fmaxf(sh_lo[0], sh_lo[1]), fmaxf(sh_lo[2], sh_lo[3]));
    atomicMax(&slot_ehi[blockIdx.x & 255], __float_as_uint(hh));
    atomicMax(&slot_elo[blockIdx.x & 255], __float_as_uint(ll));
  }
}

// One block per coarse bucket: stage entries in LDS (single global read),
// per-node counts + scan, write cnt/start, scatter within bucket region.
// No degree partition, no cross-block atomics. Unstaged fallback for
// adversarial buckets (> FS_CAP entries).
__global__ void k_finesort(const unsigned long long* cbuf64, const unsigned* cbuf32,
                           const unsigned* cstart,
                           unsigned long long* opay, unsigned* order32,
                           unsigned* cnt, unsigned* start,
                           int N, int bsh, int full) {
  __shared__ unsigned h[256], lofs[256], cur[256];
  __shared__ unsigned long long ent[FS_CAP];
  int b = blockIdx.x;
  unsigned rbase = cstart[b], rend = cstart[b + 1];
  unsigned n = rend - rbase;
  int t = threadIdx.x;
  h[t] = 0u;
  __syncthreads();
  bool staged = (n <= (unsigned)FS_CAP);
  if (staged) {
    for (unsigned j = (unsigned)t; j < n; j += 256) {
      unsigned long long v = full ? cbuf64[rbase + j]
                                  : (unsigned long long)cbuf32[rbase + j];
      ent[j] = v;
      unsigned loc = full ? (unsigned)(v >> 56) : (((unsigned)v) >> 24);
      atomicAdd(&h[loc], 1u);
    }
  } else {
    for (unsigned j = rbase + (unsigned)t; j < rend; j += 256) {
      unsigned loc = full ? (unsigned)(cbuf64[j] >> 56) : (cbuf32[j] >> 24);
      atomicAdd(&h[loc], 1u);
    }
  }
  __syncthreads();
  lofs[t] = h[t];
  __syncthreads();
  for (int off = 1; off < 256; off <<= 1) {
    unsigned v = (t >= off) ? lofs[t - off] : 0u;
    __syncthreads();
    lofs[t] += v;
    __syncthreads();
  }
  unsigned dcount = h[t];
  unsigned excl = lofs[t] - dcount;
  cur[t] = excl;
  int nper = 1 << bsh;
  int node = (b << bsh) + t;
  bool valid = (t < nper) && (node < N);
  if (valid) { cnt[node] = dcount; start[node] = rbase + excl; }
  __syncthreads();
  if (staged) {
    for (unsigned j = (unsigned)t; j < n; j += 256) {
      unsigned long long v = ent[j];
      unsigned loc = full ? (unsigned)(v >> 56) : (((unsigned)v) >> 24);
      unsigned pos = rbase + atomicAdd(&cur[loc], 1u);
      if (full) opay[pos] = v; else order32[pos] = (unsigned)v & 0x00FFFFFFu;
    }
  } else {
    for (unsigned j = rbase + (unsigned)t; j < rend; j += 256) {
      if (full) {
        unsigned long long v = cbuf64[j];
        unsigned pos = rbase + atomicAdd(&cur[(unsigned)(v >> 56)], 1u);
        opay[pos] = v;
      } else {
        unsigned v = cbuf32[j];
        unsigned pos = rbase + atomicAdd(&cur[v >> 24], 1u);
        order32[pos] = v & 0x00FFFFFFu;
      }
    }
  }
  __syncthreads();
  if (valid && dcount > 64u) {  // practically never; correctness fallback
    unsigned s0 = rbase + excl;
    if (full) {
      for (unsigned i = 1; i < dcount; i++) {
        unsigned long long key = opay[s0 + i];
        unsigned kk = (unsigned)key & 0xFFFFFFu;
        int j = (int)i - 1;
        while (j >= 0 && ((unsigned)opay[s0 + j] & 0xFFFFFFu) > kk) {
          opay[s0 + j + 1] = opay[s0 + j]; j--;
        }
        opay[s0 + (unsigned)(j + 1)] = key;
      }
    } else {
      for (unsigned i = 1; i < dcount; i++) {
        unsigned key = order32[s0 + i];
        int j = (int)i - 1;
        while (j >= 0 && order32[s0 + j] > key) { order32[s0 + j + 1] = order32[s0 + j]; j--; }
        order32[s0 + (unsigned)(j + 1)] = key;
      }
    }
  }
}

// Quantize rows. mode2: hi rows -> int8 xq8; lo rows -> packed 4-bit xq4
// (code+8 in [1,15], bit-exact nibble roundtrip). mode1: int8 for all.
// Scales computed inline from slots.
__global__ void k_quant48(const float* x, signed char* xq8, unsigned char* xq4,
                          const unsigned char* msk,
                          const unsigned* slot_ehi, const unsigned* slot_elo,
                          int N, int mode) {
  int lane = threadIdx.x & 63;
  float shi, slo;
  slot_scales(slot_ehi, slot_elo, lane, 127.0f, 7.0f, shi, slo);
  int w = (int)((blockIdx.x * blockDim.x + threadIdx.x) >> 6);
  if (w >= N) return;
  bool m = msk[w] != 0;
  float sc = m ? shi : slo;
  float qm = m ? 127.0f : 7.0f;
  float t = __fdiv_rn(x[(size_t)w * 64 + lane], sc);
  t = fminf(fmaxf(t, -qm), qm);
  t = rintf(t);
  if (mode == 2 && !m) {
    int nib = (int)t + 8;  // 1..15
    int other = __shfl_xor(nib, 1);
    if (!(lane & 1)) xq4[(size_t)w * 32 + (lane >> 1)] = (unsigned char)(nib | (other << 4));
  } else {
    xq8[(size_t)w * 64 + lane] = (signed char)t;
  }
}

// Final fake-quant of output rows (in-place). Scales inline from out-slots.
__global__ void k_quant_rows(const float* in, float* out, const unsigned char* msk,
                             const unsigned* slot_ohi, const unsigned* slot_olo,
                             int N) {
  int lane = threadIdx.x & 63;
  float shi, slo;
  slot_scales(slot_ohi, slot_olo, lane, 127.0f, 7.0f, shi, slo);
  int w = (int)((blockIdx.x * blockDim.x + threadIdx.x) >> 6);
  if (w >= N) return;
  bool m = msk[w] != 0;
  float sc = m ? shi : slo;
  float qm = m ? 127.0f : 7.0f;
  float v = in[(size_t)w * 64 + lane];
  float t = __fdiv_rn(v, sc);
  t = fminf(fmaxf(t, -qm), qm);
  t = rintf(t);
  out[(size_t)w * 64 + lane] = __fmul_rn(sc, t);
}

// Small nodes (d<=16), direct node indexing: 16-lane group per node, lane =
// 4 features, bitonic-16 order restore, 16 gathers in flight. Register-lean.
__global__ void k_aggr_small(const signed char* xq8, const unsigned char* xq4,
                             const unsigned long long* opay, const unsigned* order32,
                             const int* src, const unsigned char* msk,
                             const unsigned* start, const unsigned* cnt,
                             const unsigned* slot_ehi, const unsigned* slot_elo,
                             unsigned* slot_ohi, unsigned* slot_olo,
                             float* out, int N, int mode) {
  int lane = threadIdx.x & 63;
  float shi, slo;
  slot_scales(slot_ehi, slot_elo, lane, 127.0f, 7.0f, shi, slo);
  int t = blockIdx.x * blockDim.x + threadIdx.x;
  int node = t >> 4;
  int g = threadIdx.x & 15;
  if (node >= N) return;
  unsigned d = cnt[node];
  if (d > 16u) return;
  unsigned s0 = start[node];

  unsigned key = 0xFFFFFFFFu, pay = 0u;
  if ((unsigned)g < d) {
    if (mode == 2) {
      unsigned long long v = opay[s0 + (unsigned)g];
      key = (unsigned)v & 0xFFFFFFu;
      pay = ((unsigned)(v >> 32) & 0xFFFFFFu) | (((unsigned)(v >> 24) & 1u) << 31);
    } else {
      unsigned e = order32[s0 + (unsigned)g];
      int s = src[e];
      key = e;
      pay = (unsigned)s | (((unsigned)msk[s]) << 31);
    }
  }
  #pragma unroll
  for (int size = 2; size <= 16; size <<= 1) {
    #pragma unroll
    for (int stride = size >> 1; stride > 0; stride >>= 1) {
      unsigned ok = __shfl_xor(key, stride);
      unsigned op = __shfl_xor(pay, stride);
      bool up = ((g & size) == 0);
      bool keepMin = (((g & stride) == 0) == up);
      bool sw = keepMin ? (ok < key) : (ok > key);
      if (sw) { key = ok; pay = op; }
    }
  }
  int gbase = threadIdx.x & ~15;
  unsigned wv[16];
  #pragma unroll
  for (int j = 0; j < 16; j++) {
    int sl = gbase + ((j < (int)d) ? j : 0);
    unsigned p = __shfl(pay, sl);
    unsigned sn = p & 0x7FFFFFFFu;
    if (mode == 2 && !(p >> 31))
      wv[j] = *(const unsigned short*)(xq4 + (size_t)sn * 32 + g * 2);
    else
      wv[j] = *(const unsigned*)(xq8 + (size_t)sn * 64 + g * 4);
  }
  float acc0 = 0.0f, acc1 = 0.0f, acc2 = 0.0f, acc3 = 0.0f;
  #pragma unroll
  for (int j = 0; j < 16; j++) {
    int sl = gbase + ((j < (int)d) ? j : 0);
    unsigned p = __shfl(pay, sl);
    bool hi = (p >> 31) != 0;
    float s = (j < (int)d) ? (hi ? shi : slo) : 0.0f;  // 0-scale pads: +-0 adds
    unsigned w = wv[j];
    if (mode == 2 && !hi) {
      acc0 = __fadd_rn(acc0, __fmul_rn(s, (float)((int)(w & 15) - 8)));
      acc1 = __fadd_rn(acc1, __fmul_rn(s, (float)((int)((w >> 4) & 15) - 8)));
      acc2 = __fadd_rn(acc2, __fmul_rn(s, (float)((int)((w >> 8) & 15) - 8)));
      acc3 = __fadd_rn(acc3, __fmul_rn(s, (float)((int)((w >> 12) & 15) - 8)));
    } else {
      acc0 = __fadd_rn(acc0, __fmul_rn(s, (float)(int)(signed char)(w & 0xFF)));
      acc1 = __fadd_rn(acc1, __fmul_rn(s, (float)(int)(signed char)((w >> 8) & 0xFF)));
      acc2 = __fadd_rn(acc2, __fmul_rn(s, (float)(int)(signed char)((w >> 16) & 0xFF)));
      acc3 = __fadd_rn(acc3, __fmul_rn(s, (float)(int)(signed char)((w >> 24) & 0xFF)));
    }
  }
  float4 o4; o4.x = acc0; o4.y = acc1; o4.z = acc2; o4.w = acc3;
  *(float4*)(out + (size_t)node * 64 + g * 4) = o4;

  float a = fmaxf(fmaxf(fabsf(acc0), fabsf(acc1)), fmaxf(fabsf(acc2), fabsf(acc3)));
  #pragma unroll
  for (int o = 8; o; o >>= 1) a = fmaxf(a, __shfl_xor(a, o));
  if (g == 0) {
    unsigned* sl = msk[node] ? slot_ohi : slot_olo;
    atomicMax(&sl[node & 255], __float_as_uint(a));
  }
}

// Wave-per-node path, direct node indexing: big nodes (skip_small) or all
// nodes (mode0).
__global__ void k_aggr_wave(const signed char* xq8, const unsigned char* xq4,
                            const float* x,
                            const unsigned long long* opay, const unsigned* order32,
                            const int* src, const unsigned char* msk,
                            const unsigned* start, const unsigned* cnt,
                            const unsigned* slot_ehi, const unsigned* slot_elo,
                            unsigned* slot_ohi, unsigned* slot_olo,
                            float* out, int N, int mode, int skip_small) {
  int lane = threadIdx.x & 63;
  float shi, slo;
  slot_scales(slot_ehi, slot_elo, lane, 127.0f, 7.0f, shi, slo);
  int w = (int)((blockIdx.x * blockDim.x + threadIdx.x) >> 6);
  if (w >= N) return;
  int node = w;
  unsigned d = cnt[node];
  if (skip_small && d <= 16u) return;
  unsigned s0 = start[node];
  float acc = 0.0f;

  if (d <= 64u) {
    unsigned key = 0xFFFFFFFFu, pay = 0u;
    if ((unsigned)lane < d) {
      if (mode == 2) {
        unsigned long long v = opay[s0 + (unsigned)lane];
        key = (unsigned)v & 0xFFFFFFu;
        pay = ((unsigned)(v >> 32) & 0xFFFFFFu) | (((unsigned)(v >> 24) & 1u) << 31);
      } else {
        unsigned e = order32[s0 + (unsigned)lane];
        int s = src[e];
        key = e;
        pay = (unsigned)s | (((unsigned)msk[s]) << 31);
      }
    }
    #pragma unroll
    for (int size = 2; size <= 32; size <<= 1) {
      #pragma unroll
      for (int stride = size >> 1; stride > 0; stride >>= 1) {
        unsigned ok = __shfl_xor(key, stride);
        unsigned op = __shfl_xor(pay, stride);
        bool up = ((lane & size) == 0);
        bool keepMin = (((lane & stride) == 0) == up);
        bool sw = keepMin ? (ok < key) : (ok > key);
        if (sw) { key = ok; pay = op; }
      }
    }
    if (d > 32u) {
      #pragma unroll
      for (int stride = 32; stride > 0; stride >>= 1) {
        unsigned ok = __shfl_xor(key, stride);
        unsigned op = __shfl_xor(pay, stride);
        bool keepMin = ((lane & stride) == 0);
        bool sw = keepMin ? (ok < key) : (ok > key);
        if (sw) { key = ok; pay = op; }
      }
    }
    for (unsigned kb = 0; kb < d; kb += 16) {
      float vv[16];
      #pragma unroll
      for (int j = 0; j < 16; j++) {
        unsigned kk = kb + (unsigned)j;
        int sl = (int)(kk < d ? kk : 0u);
        unsigned p = __shfl(pay, sl);
        float sc = (p >> 31) ? shi : slo;
        float scm = (kk < d) ? sc : 0.0f;
        unsigned sn = p & 0x7FFFFFFFu;
        float q;
        if (mode == 2) {
          if (p >> 31) {
            q = (float)xq8[(size_t)sn * 64 + lane];
          } else {
            unsigned bb = xq4[(size_t)sn * 32 + (lane >> 1)];
            int nib = (lane & 1) ? (int)(bb >> 4) : (int)(bb & 15);
            q = (float)(nib - 8);
          }
        } else if (mode == 1) {
          q = (float)xq8[(size_t)sn * 64 + lane];
        } else {
          float qm = (p >> 31) ? 127.0f : 7.0f;
          float tq = __fdiv_rn(x[(size_t)sn * 64 + lane], sc);
          tq = fminf(fmaxf(tq, -qm), qm);
          q = rintf(tq);
        }
        vv[j] = __fmul_rn(scm, q);
      }
      #pragma unroll
      for (int j = 0; j < 16; j++) acc = __fadd_rn(acc, vv[j]);
    }
  } else {
    for (unsigned k = 0; k < d; k++) {
      unsigned sn; bool m;
      if (mode == 2) {
        unsigned long long v = opay[s0 + k];
        sn = (unsigned)(v >> 32) & 0xFFFFFFu;
        m = ((v >> 24) & 1ull) != 0;
      } else {
        unsigned e = order32[s0 + k];
        sn = (unsigned)src[e];
        m = msk[sn] != 0;
      }
      float sc = m ? shi : slo;
      float q;
      if (mode == 2) {
        if (m) {
          q = (float)xq8[(size_t)sn * 64 + lane];
        } else {
          unsigned bb = xq4[(size_t)sn * 32 + (lane >> 1)];
          int nib = (lane & 1) ? (int)(bb >> 4) : (int)(bb & 15);
          q = (float)(nib - 8);
        }
      } else if (mode == 1) {
        q = (float)xq8[(size_t)sn * 64 + lane];
      } else {
        float qm = m ? 127.0f : 7.0f;
        float tq = __fdiv_rn(x[(size_t)sn * 64 + lane], sc);
        tq = fminf(fmaxf(tq, -qm), qm);
        q = rintf(tq);
      }
      acc = __fadd_rn(acc, __fmul_rn(sc, q));
    }
  }

  out[(size_t)node * 64 + lane] = acc;

  float a = fabsf(acc);
  for (int o = 32; o; o >>= 1) a = fmaxf(a, __shfl_xor(a, o));
  if (lane == 0) {
    unsigned* sl = (msk[node] != 0) ? slot_ohi : slot_olo;
    atomicMax(&sl[node & 255], __float_as_uint(a));
  }
}

extern "C" void kernel_launch(void* const* d_in, const int* in_sizes, int n_in,
                              void* d_out, int out_size, void* d_ws, size_t ws_size,
                              hipStream_t stream) {
  const float* x = (const float*)d_in[0];
  const int* ei = (const int*)d_in[1];
  const void* mraw = d_in[2];
  int N = in_sizes[2];
  int E = in_sizes[1] / 2;
  const int* src = ei;
  const int* dst = ei + E;
  float* out = (float*)d_out;

  int bsh = 7;
  while ((((N - 1) >> bsh) + 1) > 1024 && bsh < 8) bsh++;
  int NB = ((N - 1) >> bsh) + 1;
  int vec = (((uintptr_t)src & 15) == 0) && (((uintptr_t)dst & 15) == 0) && ((E & 3) == 0);

  char* ws = (char*)d_ws;
  auto al = [](size_t v) { return ((v + 255) / 256) * 256; };
  size_t o_sehi = 256, o_selo = 1280, o_sohi = 2304, o_solo = 3328;
  size_t o_ccnt = 4352;
  size_t o_cstart = al(o_ccnt + (size_t)(NB + 1) * 4);
  size_t o_bwrite = al(o_cstart + (size_t)(NB + 1) * 4);
  size_t o_msk = al(o_bwrite + (size_t)NB * 4);
  size_t o_rowmax = al(o_msk + (size_t)N);
  size_t o_cnt = o_rowmax + (size_t)N * 4;
  size_t o_start = o_cnt + (size_t)N * 4;
  size_t o_cbuf = al(o_start + (size_t)N * 4);

  // FULL layout
  size_t o_opay = al(o_cbuf + (size_t)E * 8);
  size_t o_xq4 = al(o_opay + (size_t)E * 8);
  size_t o_xq8f = al(o_xq4 + (size_t)N * 32);
  size_t need_full = o_xq8f + (size_t)N * 64;
  // COMPAT layout
  size_t o_order_c = al(o_cbuf + (size_t)E * 4);
  size_t o_xq8c = al(o_order_c + (size_t)E * 4);
  size_t need_compat = o_xq8c + (size_t)N * 64;

  int mode;
  if (ws_size >= need_full && E < (1 << 24) && N < (1 << 24)) mode = 2;
  else if (ws_size >= need_compat && E < (1 << 24)) mode = 1;
  else mode = 0;

  unsigned* head = (unsigned*)ws;
  unsigned* slot_ehi = (unsigned*)(ws + o_sehi);
  unsigned* slot_elo = (unsigned*)(ws + o_selo);
  unsigned* slot_ohi = (unsigned*)(ws + o_sohi);
  unsigned* slot_olo = (unsigned*)(ws + o_solo);
  unsigned* ccnt = (unsigned*)(ws + o_ccnt);
  unsigned* cstart = (unsigned*)(ws + o_cstart);
  unsigned* bwrite = (unsigned*)(ws + o_bwrite);
  unsigned char* msk = (unsigned char*)(ws + o_msk);
  float* rowmax = (float*)(ws + o_rowmax);
  unsigned* cnt = (unsigned*)(ws + o_cnt);
  unsigned* start = (unsigned*)(ws + o_start);
  unsigned long long* cbuf64 = (unsigned long long*)(ws + o_cbuf);
  unsigned* cbuf32 = (unsigned*)(ws + o_cbuf);
  unsigned long long* opay = (unsigned long long*)(ws + o_opay);
  unsigned* order32 = (unsigned*)(ws + o_order_c);
  unsigned char* xq4 = (unsigned char*)(ws + o_xq4);
  signed char* xq8 = (signed char*)(ws + ((mode == 2) ? o_xq8f : o_xq8c));

  int rowBlocks = (N + 3) / 4;
  int nbp = (E + BP_CHUNK - 1) / BP_CHUNK;
  int full = (mode == 2);

  k_zero<<<8, 256, 0, stream>>>(head, (int)(o_cstart / 4));
  k_detect<<<256, 256, 0, stream>>>((const unsigned char*)mraw, head, N);
  k_rowmax_canon<<<rowBlocks, 256, 0, stream>>>(x, mraw, head, rowmax, msk, N);
  k_edge_hist<<<256, 256, 0, stream>>>(dst, ccnt, E, NB, bsh, vec);
  k_cscan<<<1, 256, 0, stream>>>(ccnt, cstart, bwrite, NB);
  k_binplace<<<nbp, 256, 0, stream>>>(src, dst, msk, rowmax, bwrite, cbuf64, cbuf32,
                                      slot_ehi, slot_elo, E, NB, bsh, full, vec);
  if (mode >= 1)
    k_quant48<<<rowBlocks, 256, 0, stream>>>(x, xq8, xq4, msk, slot_ehi, slot_elo, N, mode);
  k_finesort<<<NB, 256, 0, stream>>>(cbuf64, cbuf32, cstart, opay, order32,
                                     cnt, start, N, bsh, full);
  if (mode >= 1) {
    k_aggr_small<<<(N + 15) / 16, 256, 0, stream>>>(xq8, xq4, opay, order32, src, msk,
                                                    start, cnt, slot_ehi, slot_elo,
                                                    slot_ohi, slot_olo, out, N, mode);
    k_aggr_wave<<<rowBlocks, 256, 0, stream>>>(xq8, xq4, x, opay, order32, src, msk,
                                               start, cnt, slot_ehi, slot_elo,
                                               slot_ohi, slot_olo, out, N, mode, 1);
  } else {
    k_aggr_wave<<<rowBlocks, 256, 0, stream>>>(xq8, xq4, x, opay, order32, src, msk,
                                               start, cnt, slot_ehi, slot_elo,
                                               slot_ohi, slot_olo, out, N, mode, 0);
  }
  k_quant_rows<<<rowBlocks, 256, 0, stream>>>(out, out, msk, slot_ohi, slot_olo, N);
}

// Round 9
// 225.805 us; speedup vs baseline: 1.0513x; 1.0513x over previous
//
#include <hip/hip_runtime.h>

// head u32 words: 0:c0 1:c123 | hf[6]=shi_msg hf[7]=slo_msg hf[8]=shi_out hf[9]=slo_out
// FULL (mode 2): binplace packs u64 (local<<56)|(src<<32)|(msk<<24)|e ; finesort -> opay u64;
//   lo rows 4-bit plane xq4 (N*32 B), hi rows int8 xq8 (N*64 B).
// COMPAT (mode 1): u32 cbuf/order, xq8 for all rows, aggr gathers src/msk.
// RAW (mode 0): u32 cbuf/order, aggr quantizes from x on the fly.
// Constraints: E < 2^24, N < 2^24, bsh <= 8.

#define BP_CHUNK 4096
#define FS_CAP 2560

__global__ void k_zero(unsigned* p, int n) {
  int i = blockIdx.x * blockDim.x + threadIdx.x;
  for (; i < n; i += gridDim.x * blockDim.x) p[i] = 0u;
}

// Sniff mask dtype from raw bytes (reads only N bytes, safe for u8/i32/f32).
__global__ void k_detect(const unsigned char* m, unsigned* head, int nbytes) {
  int i = blockIdx.x * blockDim.x + threadIdx.x;
  int c0 = 0, c123 = 0;
  for (; i < nbytes; i += gridDim.x * blockDim.x) {
    unsigned char b = m[i];
    if (b) { if ((i & 3) == 0) c0++; else c123++; }
  }
  for (int o = 32; o; o >>= 1) { c0 += __shfl_xor(c0, o); c123 += __shfl_xor(c123, o); }
  if ((threadIdx.x & 63) == 0) {
    if (c0)   atomicAdd(&head[0], (unsigned)c0);
    if (c123) atomicAdd(&head[1], (unsigned)c123);
  }
}

// Canonicalize mask to u8 (thread per node) + rowmax (wave per node).
__global__ void k_rowmax_canon(const float* x, const void* mraw, const unsigned* head,
                               float* rowmax, unsigned char* msk, int N) {
  int gid = blockIdx.x * blockDim.x + threadIdx.x;
  if (gid < N) {
    unsigned c0 = head[0], c123 = head[1];
    int mode = (c123 == 0u) ? 1 : ((c0 == 0u) ? 2 : 0);
    unsigned char v;
    if (mode == 0)      v = (((const unsigned char*)mraw)[gid] != 0);
    else if (mode == 1) v = (((const int*)mraw)[gid] != 0);
    else                v = (((const float*)mraw)[gid] != 0.0f);
    msk[gid] = v;
  }
  int w = gid >> 6;
  int lane = threadIdx.x & 63;
  if (w >= N) return;
  float v = fabsf(x[(size_t)w * 64 + lane]);
  for (int o = 32; o; o >>= 1) v = fmaxf(v, __shfl_xor(v, o));
  if (lane == 0) rowmax[w] = v;
}

// Coarse histogram of dst>>bsh in LDS (vec4 reads), one global flush per block.
__global__ void k_edge_hist(const int* dst, unsigned* ccnt, int E, int NB, int bsh, int vec) {
  __shared__ unsigned h[1024];
  for (int i = threadIdx.x; i < NB; i += 256) h[i] = 0u;
  __syncthreads();
  int tid = blockIdx.x * blockDim.x + threadIdx.x;
  int st = gridDim.x * blockDim.x;
  int E4 = vec ? (E >> 2) : 0;
  const int4* d4 = (const int4*)dst;
  for (int i = tid; i < E4; i += st) {
    int4 v = d4[i];
    atomicAdd(&h[((unsigned)v.x) >> bsh], 1u);
    atomicAdd(&h[((unsigned)v.y) >> bsh], 1u);
    atomicAdd(&h[((unsigned)v.z) >> bsh], 1u);
    atomicAdd(&h[((unsigned)v.w) >> bsh], 1u);
  }
  for (int e = E4 * 4 + tid; e < E; e += st)
    atomicAdd(&h[((unsigned)dst[e]) >> bsh], 1u);
  __syncthreads();
  for (int i = threadIdx.x; i < NB; i += 256)
    if (h[i]) atomicAdd(&ccnt[i], h[i]);
}

// One-block exclusive scan of ccnt[NB] -> cstart[NB+1]; also init bwrite=cstart.
__global__ void k_cscan(const unsigned* ccnt, unsigned* cstart, unsigned* bwrite, int NB) {
  __shared__ unsigned sh[1024];
  int t = threadIdx.x;
  for (int i = t; i < 1024; i += 256) sh[i] = (i < NB) ? ccnt[i] : 0u;
  __syncthreads();
  for (int off = 1; off < 1024; off <<= 1) {
    unsigned v[4];
    #pragma unroll
    for (int j = 0; j < 4; j++) { int i = t + j * 256; v[j] = (i >= off) ? sh[i - off] : 0u; }
    __syncthreads();
    #pragma unroll
    for (int j = 0; j < 4; j++) { int i = t + j * 256; sh[i] += v[j]; }
    __syncthreads();
  }
  for (int i = t; i < 1024; i += 256) {
    unsigned excl = (i == 0) ? 0u : sh[i - 1];
    if (i < NB) { cstart[i] = excl; bwrite[i] = excl; }
    if (i == NB - 1) cstart[NB] = sh[i];
  }
}

// Coarse binning: LDS hist -> bulk reservation -> scatter (u64 in FULL mode,
// carrying src+msk so aggregation never re-gathers them). Also per-edge class
// amax of rowmax[src] into spread slots.
__global__ void k_binplace(const int* src, const int* dst, const unsigned char* msk,
                           const float* rowmax, unsigned* bwrite,
                           unsigned long long* cbuf64, unsigned* cbuf32,
                           unsigned* slot_ehi, unsigned* slot_elo,
                           int E, int NB, int bsh, int full, int vec) {
  __shared__ unsigned h[1024], base[1024];
  __shared__ float sh_hi[4], sh_lo[4];
  int cbase = blockIdx.x * BP_CHUNK;
  int cend = cbase + BP_CHUNK; if (cend > E) cend = E;
  int n = cend - cbase;
  int n4 = vec ? (n >> 2) : 0;
  for (int i = threadIdx.x; i < NB; i += 256) h[i] = 0u;
  __syncthreads();
  const int4* d4 = (const int4*)(dst + cbase);
  const int4* s4 = (const int4*)(src + cbase);
  for (int i = threadIdx.x; i < n4; i += 256) {
    int4 v = d4[i];
    atomicAdd(&h[((unsigned)v.x) >> bsh], 1u);
    atomicAdd(&h[((unsigned)v.y) >> bsh], 1u);
    atomicAdd(&h[((unsigned)v.z) >> bsh], 1u);
    atomicAdd(&h[((unsigned)v.w) >> bsh], 1u);
  }
  for (int e = cbase + n4 * 4 + threadIdx.x; e < cend; e += 256)
    atomicAdd(&h[((unsigned)dst[e]) >> bsh], 1u);
  __syncthreads();
  for (int i = threadIdx.x; i < NB; i += 256) {
    unsigned c = h[i];
    base[i] = c ? atomicAdd(&bwrite[i], c) : 0u;
    h[i] = 0u;  // reuse as cursor
  }
  __syncthreads();
  unsigned lmask = (1u << bsh) - 1u;
  float hi = 0.0f, lo = 0.0f;
  for (int i = threadIdx.x; i < n4; i += 256) {
    int4 dv = d4[i]; int4 sv = s4[i];
    int e0 = cbase + i * 4;
    int dd[4] = {dv.x, dv.y, dv.z, dv.w};
    int ss[4] = {sv.x, sv.y, sv.z, sv.w};
    #pragma unroll
    for (int j = 0; j < 4; j++) {
      int d = dd[j], s = ss[j];
      unsigned mk = msk[s];
      float r = rowmax[s];
      if (mk) hi = fmaxf(hi, r); else lo = fmaxf(lo, r);
      unsigned b = (unsigned)d >> bsh;
      unsigned pos = base[b] + atomicAdd(&h[b], 1u);
      if (full)
        cbuf64[pos] = ((unsigned long long)(((((unsigned)d) & lmask) << 24) | (unsigned)s) << 32)
                      | ((mk << 24) | (unsigned)(e0 + j));
      else
        cbuf32[pos] = ((((unsigned)d) & lmask) << 24) | (unsigned)(e0 + j);
    }
  }
  for (int e = cbase + n4 * 4 + threadIdx.x; e < cend; e += 256) {
    int d = dst[e], s = src[e];
    unsigned mk = msk[s];
    float r = rowmax[s];
    if (mk) hi = fmaxf(hi, r); else lo = fmaxf(lo, r);
    unsigned b = (unsigned)d >> bsh;
    unsigned pos = base[b] + atomicAdd(&h[b], 1u);
    if (full)
      cbuf64[pos] = ((unsigned long long)(((((unsigned)d) & lmask) << 24) | (unsigned)s) << 32)
                    | ((mk << 24) | (unsigned)e);
    else
      cbuf32[pos] = ((((unsigned)d) & lmask) << 24) | (unsigned)e;
  }
  for (int o = 32; o; o >>= 1) { hi = fmaxf(hi, __shfl_xor(hi, o)); lo = fmaxf(lo, __shfl_xor(lo, o)); }
  int wid = threadIdx.x >> 6, lane = threadIdx.x & 63;
  if (lane == 0) { sh_hi[wid] = hi; sh_lo[wid] = lo; }
  __syncthreads();
  if (threadIdx.x == 0) {
    float hh = fmaxf(fmaxf(sh_hi[0], sh_hi[1]), fmaxf(sh_hi[2], sh_hi[3]));
    float ll = fmaxf(fmaxf(sh_lo[0], sh_lo[1]), fmaxf(sh_lo[2], sh_lo[3]));
    atomicMax(&slot_ehi[blockIdx.x & 255], __float_as_uint(hh));
    atomicMax(&slot_elo[blockIdx.x & 255], __float_as_uint(ll));
  }
}

// One block per coarse bucket: stage entries in LDS (single global read),
// per-node counts + scan, write cnt/start, scatter within bucket region.
// Unstaged fallback for adversarial buckets (> FS_CAP entries).
__global__ void k_finesort(const unsigned long long* cbuf64, const unsigned* cbuf32,
                           const unsigned* cstart,
                           unsigned long long* opay, unsigned* order32,
                           unsigned* cnt, unsigned* start,
                           int N, int bsh, int full) {
  __shared__ unsigned h[256], lofs[256], cur[256];
  __shared__ unsigned long long ent[FS_CAP];
  int b = blockIdx.x;
  unsigned rbase = cstart[b], rend = cstart[b + 1];
  unsigned n = rend - rbase;
  int t = threadIdx.x;
  h[t] = 0u;
  __syncthreads();
  bool staged = (n <= (unsigned)FS_CAP);
  if (staged) {
    for (unsigned j = (unsigned)t; j < n; j += 256) {
      unsigned long long v = full ? cbuf64[rbase + j]
                                  : (unsigned long long)cbuf32[rbase + j];
      ent[j] = v;
      unsigned loc = full ? (unsigned)(v >> 56) : (((unsigned)v) >> 24);
      atomicAdd(&h[loc], 1u);
    }
  } else {
    for (unsigned j = rbase + (unsigned)t; j < rend; j += 256) {
      unsigned loc = full ? (unsigned)(cbuf64[j] >> 56) : (cbuf32[j] >> 24);
      atomicAdd(&h[loc], 1u);
    }
  }
  __syncthreads();
  lofs[t] = h[t];
  __syncthreads();
  for (int off = 1; off < 256; off <<= 1) {
    unsigned v = (t >= off) ? lofs[t - off] : 0u;
    __syncthreads();
    lofs[t] += v;
    __syncthreads();
  }
  unsigned dcount = h[t];
  unsigned excl = lofs[t] - dcount;
  cur[t] = excl;
  int nper = 1 << bsh;
  int node = (b << bsh) + t;
  bool valid = (t < nper) && (node < N);
  if (valid) { cnt[node] = dcount; start[node] = rbase + excl; }
  __syncthreads();
  if (staged) {
    for (unsigned j = (unsigned)t; j < n; j += 256) {
      unsigned long long v = ent[j];
      unsigned loc = full ? (unsigned)(v >> 56) : (((unsigned)v) >> 24);
      unsigned pos = rbase + atomicAdd(&cur[loc], 1u);
      if (full) opay[pos] = v; else order32[pos] = (unsigned)v & 0x00FFFFFFu;
    }
  } else {
    for (unsigned j = rbase + (unsigned)t; j < rend; j += 256) {
      if (full) {
        unsigned long long v = cbuf64[j];
        unsigned pos = rbase + atomicAdd(&cur[(unsigned)(v >> 56)], 1u);
        opay[pos] = v;
      } else {
        unsigned v = cbuf32[j];
        unsigned pos = rbase + atomicAdd(&cur[v >> 24], 1u);
        order32[pos] = v & 0x00FFFFFFu;
      }
    }
  }
  __syncthreads();
  if (valid && dcount > 64u) {  // practically never; correctness fallback
    unsigned s0 = rbase + excl;
    if (full) {
      for (unsigned i = 1; i < dcount; i++) {
        unsigned long long key = opay[s0 + i];
        unsigned kk = (unsigned)key & 0xFFFFFFu;
        int j = (int)i - 1;
        while (j >= 0 && ((unsigned)opay[s0 + j] & 0xFFFFFFu) > kk) {
          opay[s0 + j + 1] = opay[s0 + j]; j--;
        }
        opay[s0 + (unsigned)(j + 1)] = key;
      }
    } else {
      for (unsigned i = 1; i < dcount; i++) {
        unsigned key = order32[s0 + i];
        int j = (int)i - 1;
        while (j >= 0 && order32[s0 + j] > key) { order32[s0 + j + 1] = order32[s0 + j]; j--; }
        order32[s0 + (unsigned)(j + 1)] = key;
      }
    }
  }
}

// Reduce 256-slot amax arrays -> scales in head. which=0: msg; which=1: out.
__global__ void k_scales(unsigned* head, const unsigned* shi, const unsigned* slo, int which) {
  __shared__ unsigned smh[256], sml[256];
  int t = threadIdx.x;
  smh[t] = shi[t]; sml[t] = slo[t];
  __syncthreads();
  for (int off = 128; off > 0; off >>= 1) {
    if (t < off) {
      smh[t] = smh[t] > smh[t + off] ? smh[t] : smh[t + off];
      sml[t] = sml[t] > sml[t + off] ? sml[t] : sml[t + off];
    }
    __syncthreads();
  }
  if (t == 0) {
    float* hf = (float*)head;
    float ah = __uint_as_float(smh[0]);
    float al = __uint_as_float(sml[0]);
    hf[6 + which * 2]     = __fdiv_rn(fmaxf(ah, 1e-8f), 127.0f);
    hf[6 + which * 2 + 1] = __fdiv_rn(fmaxf(al, 1e-8f), 7.0f);
  }
}

// Quantize rows. mode2: hi rows -> int8 xq8; lo rows -> packed 4-bit xq4
// (code+8 in [1,15], bit-exact nibble roundtrip). mode1: int8 for all.
__global__ void k_quant48(const float* x, signed char* xq8, unsigned char* xq4,
                          const unsigned char* msk, const unsigned* head,
                          int N, int mode) {
  int w = (int)((blockIdx.x * blockDim.x + threadIdx.x) >> 6);
  int lane = threadIdx.x & 63;
  if (w >= N) return;
  const float* hf = (const float*)head;
  bool m = msk[w] != 0;
  float sc = m ? hf[6] : hf[7];
  float qm = m ? 127.0f : 7.0f;
  float t = __fdiv_rn(x[(size_t)w * 64 + lane], sc);
  t = fminf(fmaxf(t, -qm), qm);
  t = rintf(t);
  if (mode == 2 && !m) {
    int nib = (int)t + 8;  // 1..15
    int other = __shfl_xor(nib, 1);
    if (!(lane & 1)) xq4[(size_t)w * 32 + (lane >> 1)] = (unsigned char)(nib | (other << 4));
  } else {
    xq8[(size_t)w * 64 + lane] = (signed char)t;
  }
}

// Final fake-quant of output rows (in-place, float).
__global__ void k_quant_rows(const float* in, float* out, const unsigned char* msk,
                             const unsigned* head, int N) {
  int w = (int)((blockIdx.x * blockDim.x + threadIdx.x) >> 6);
  int lane = threadIdx.x & 63;
  if (w >= N) return;
  const float* hf = (const float*)head;
  bool m = msk[w] != 0;
  float sc = m ? hf[8] : hf[9];
  float qm = m ? 127.0f : 7.0f;
  float v = in[(size_t)w * 64 + lane];
  float t = __fdiv_rn(v, sc);
  t = fminf(fmaxf(t, -qm), qm);
  t = rintf(t);
  out[(size_t)w * 64 + lane] = __fmul_rn(sc, t);
}

// Small nodes (d<=16), direct node indexing: 16-lane group per node, lane =
// 4 features, bitonic-16 order restore, 16 gathers in flight. Register-lean.
__global__ void k_aggr_small(const signed char* xq8, const unsigned char* xq4,
                             const unsigned long long* opay, const unsigned* order32,
                             const int* src, const unsigned char* msk,
                             const unsigned* start, const unsigned* cnt,
                             const unsigned* head,
                             unsigned* slot_ohi, unsigned* slot_olo,
                             float* out, int N, int mode) {
  int t = blockIdx.x * blockDim.x + threadIdx.x;
  int node = t >> 4;
  int g = threadIdx.x & 15;
  if (node >= N) return;
  unsigned d = cnt[node];
  if (d > 16u) return;
  unsigned s0 = start[node];
  const float* hf = (const float*)head;
  float shi = hf[6], slo = hf[7];

  unsigned key = 0xFFFFFFFFu, pay = 0u;
  if ((unsigned)g < d) {
    if (mode == 2) {
      unsigned long long v = opay[s0 + (unsigned)g];
      key = (unsigned)v & 0xFFFFFFu;
      pay = ((unsigned)(v >> 32) & 0xFFFFFFu) | (((unsigned)(v >> 24) & 1u) << 31);
    } else {
      unsigned e = order32[s0 + (unsigned)g];
      int s = src[e];
      key = e;
      pay = (unsigned)s | (((unsigned)msk[s]) << 31);
    }
  }
  #pragma unroll
  for (int size = 2; size <= 16; size <<= 1) {
    #pragma unroll
    for (int stride = size >> 1; stride > 0; stride >>= 1) {
      unsigned ok = __shfl_xor(key, stride);
      unsigned op = __shfl_xor(pay, stride);
      bool up = ((g & size) == 0);
      bool keepMin = (((g & stride) == 0) == up);
      bool sw = keepMin ? (ok < key) : (ok > key);
      if (sw) { key = ok; pay = op; }
    }
  }
  int gbase = threadIdx.x & ~15;
  unsigned wv[16];
  #pragma unroll
  for (int j = 0; j < 16; j++) {
    int sl = gbase + ((j < (int)d) ? j : 0);
    unsigned p = __shfl(pay, sl);
    unsigned sn = p & 0x7FFFFFFFu;
    if (mode == 2 && !(p >> 31))
      wv[j] = *(const unsigned short*)(xq4 + (size_t)sn * 32 + g * 2);
    else
      wv[j] = *(const unsigned*)(xq8 + (size_t)sn * 64 + g * 4);
  }
  float acc0 = 0.0f, acc1 = 0.0f, acc2 = 0.0f, acc3 = 0.0f;
  #pragma unroll
  for (int j = 0; j < 16; j++) {
    int sl = gbase + ((j < (int)d) ? j : 0);
    unsigned p = __shfl(pay, sl);
    bool hi = (p >> 31) != 0;
    float s = (j < (int)d) ? (hi ? shi : slo) : 0.0f;  // 0-scale pads: +-0 adds
    unsigned w = wv[j];
    if (mode == 2 && !hi) {
      acc0 = __fadd_rn(acc0, __fmul_rn(s, (float)((int)(w & 15) - 8)));
      acc1 = __fadd_rn(acc1, __fmul_rn(s, (float)((int)((w >> 4) & 15) - 8)));
      acc2 = __fadd_rn(acc2, __fmul_rn(s, (float)((int)((w >> 8) & 15) - 8)));
      acc3 = __fadd_rn(acc3, __fmul_rn(s, (float)((int)((w >> 12) & 15) - 8)));
    } else {
      acc0 = __fadd_rn(acc0, __fmul_rn(s, (float)(int)(signed char)(w & 0xFF)));
      acc1 = __fadd_rn(acc1, __fmul_rn(s, (float)(int)(signed char)((w >> 8) & 0xFF)));
      acc2 = __fadd_rn(acc2, __fmul_rn(s, (float)(int)(signed char)((w >> 16) & 0xFF)));
      acc3 = __fadd_rn(acc3, __fmul_rn(s, (float)(int)(signed char)((w >> 24) & 0xFF)));
    }
  }
  float4 o4; o4.x = acc0; o4.y = acc1; o4.z = acc2; o4.w = acc3;
  *(float4*)(out + (size_t)node * 64 + g * 4) = o4;

  float a = fmaxf(fmaxf(fabsf(acc0), fabsf(acc1)), fmaxf(fabsf(acc2), fabsf(acc3)));
  #pragma unroll
  for (int o = 8; o; o >>= 1) a = fmaxf(a, __shfl_xor(a, o));
  if (g == 0) {
    unsigned* sl = msk[node] ? slot_ohi : slot_olo;
    atomicMax(&sl[node & 255], __float_as_uint(a));
  }
}

// Wave-per-node path, direct node indexing: big nodes (skip_small) or all
// nodes (mode0).
__global__ void k_aggr_wave(const signed char* xq8, const unsigned char* xq4,
                            const float* x,
                            const unsigned long long* opay, const unsigned* order32,
                            const int* src, const unsigned char* msk,
                            const unsigned* start, const unsigned* cnt,
                            const unsigned* head,
                            unsigned* slot_ohi, unsigned* slot_olo,
                            float* out, int N, int mode, int skip_small) {
  int w = (int)((blockIdx.x * blockDim.x + threadIdx.x) >> 6);
  int lane = threadIdx.x & 63;
  if (w >= N) return;
  int node = w;
  unsigned d = cnt[node];
  if (skip_small && d <= 16u) return;
  unsigned s0 = start[node];
  const float* hf = (const float*)head;
  float shi = hf[6], slo = hf[7];
  float acc = 0.0f;

  if (d <= 64u) {
    unsigned key = 0xFFFFFFFFu, pay = 0u;
    if ((unsigned)lane < d) {
      if (mode == 2) {
        unsigned long long v = opay[s0 + (unsigned)lane];
        key = (unsigned)v & 0xFFFFFFu;
        pay = ((unsigned)(v >> 32) & 0xFFFFFFu) | (((unsigned)(v >> 24) & 1u) << 31);
      } else {
        unsigned e = order32[s0 + (unsigned)lane];
        int s = src[e];
        key = e;
        pay = (unsigned)s | (((unsigned)msk[s]) << 31);
      }
    }
    #pragma unroll
    for (int size = 2; size <= 32; size <<= 1) {
      #pragma unroll
      for (int stride = size >> 1; stride > 0; stride >>= 1) {
        unsigned ok = __shfl_xor(key, stride);
        unsigned op = __shfl_xor(pay, stride);
        bool up = ((lane & size) == 0);
        bool keepMin = (((lane & stride) == 0) == up);
        bool sw = keepMin ? (ok < key) : (ok > key);
        if (sw) { key = ok; pay = op; }
      }
    }
    if (d > 32u) {
      #pragma unroll
      for (int stride = 32; stride > 0; stride >>= 1) {
        unsigned ok = __shfl_xor(key, stride);
        unsigned op = __shfl_xor(pay, stride);
        bool keepMin = ((lane & stride) == 0);
        bool sw = keepMin ? (ok < key) : (ok > key);
        if (sw) { key = ok; pay = op; }
      }
    }
    for (unsigned kb = 0; kb < d; kb += 16) {
      float vv[16];
      #pragma unroll
      for (int j = 0; j < 16; j++) {
        unsigned kk = kb + (unsigned)j;
        int sl = (int)(kk < d ? kk : 0u);
        unsigned p = __shfl(pay, sl);
        float sc = (p >> 31) ? shi : slo;
        float scm = (kk < d) ? sc : 0.0f;
        unsigned sn = p & 0x7FFFFFFFu;
        float q;
        if (mode == 2) {
          if (p >> 31) {
            q = (float)xq8[(size_t)sn * 64 + lane];
          } else {
            unsigned bb = xq4[(size_t)sn * 32 + (lane >> 1)];
            int nib = (lane & 1) ? (int)(bb >> 4) : (int)(bb & 15);
            q = (float)(nib - 8);
          }
        } else if (mode == 1) {
          q = (float)xq8[(size_t)sn * 64 + lane];
        } else {
          float qm = (p >> 31) ? 127.0f : 7.0f;
          float tq = __fdiv_rn(x[(size_t)sn * 64 + lane], sc);
          tq = fminf(fmaxf(tq, -qm), qm);
          q = rintf(tq);
        }
        vv[j] = __fmul_rn(scm, q);
      }
      #pragma unroll
      for (int j = 0; j < 16; j++) acc = __fadd_rn(acc, vv[j]);
    }
  } else {
    for (unsigned k = 0; k < d; k++) {
      unsigned sn; bool m;
      if (mode == 2) {
        unsigned long long v = opay[s0 + k];
        sn = (unsigned)(v >> 32) & 0xFFFFFFu;
        m = ((v >> 24) & 1ull) != 0;
      } else {
        unsigned e = order32[s0 + k];
        sn = (unsigned)src[e];
        m = msk[sn] != 0;
      }
      float sc = m ? shi : slo;
      float q;
      if (mode == 2) {
        if (m) {
          q = (float)xq8[(size_t)sn * 64 + lane];
        } else {
          unsigned bb = xq4[(size_t)sn * 32 + (lane >> 1)];
          int nib = (lane & 1) ? (int)(bb >> 4) : (int)(bb & 15);
          q = (float)(nib - 8);
        }
      } else if (mode == 1) {
        q = (float)xq8[(size_t)sn * 64 + lane];
      } else {
        float qm = m ? 127.0f : 7.0f;
        float tq = __fdiv_rn(x[(size_t)sn * 64 + lane], sc);
        tq = fminf(fmaxf(tq, -qm), qm);
        q = rintf(tq);
      }
      acc = __fadd_rn(acc, __fmul_rn(sc, q));
    }
  }

  out[(size_t)node * 64 + lane] = acc;

  float a = fabsf(acc);
  for (int o = 32; o; o >>= 1) a = fmaxf(a, __shfl_xor(a, o));
  if (lane == 0) {
    unsigned* sl = (msk[node] != 0) ? slot_ohi : slot_olo;
    atomicMax(&sl[node & 255], __float_as_uint(a));
  }
}

extern "C" void kernel_launch(void* const* d_in, const int* in_sizes, int n_in,
                              void* d_out, int out_size, void* d_ws, size_t ws_size,
                              hipStream_t stream) {
  const float* x = (const float*)d_in[0];
  const int* ei = (const int*)d_in[1];
  const void* mraw = d_in[2];
  int N = in_sizes[2];
  int E = in_sizes[1] / 2;
  const int* src = ei;
  const int* dst = ei + E;
  float* out = (float*)d_out;

  int bsh = 7;
  while ((((N - 1) >> bsh) + 1) > 1024 && bsh < 8) bsh++;
  int NB = ((N - 1) >> bsh) + 1;
  int vec = (((uintptr_t)src & 15) == 0) && (((uintptr_t)dst & 15) == 0) && ((E & 3) == 0);

  char* ws = (char*)d_ws;
  auto al = [](size_t v) { return ((v + 255) / 256) * 256; };
  size_t o_sehi = 256, o_selo = 1280, o_sohi = 2304, o_solo = 3328;
  size_t o_ccnt = 4352;
  size_t o_cstart = al(o_ccnt + (size_t)(NB + 1) * 4);
  size_t o_bwrite = al(o_cstart + (size_t)(NB + 1) * 4);
  size_t o_msk = al(o_bwrite + (size_t)NB * 4);
  size_t o_rowmax = al(o_msk + (size_t)N);
  size_t o_cnt = o_rowmax + (size_t)N * 4;
  size_t o_start = o_cnt + (size_t)N * 4;
  size_t o_cbuf = al(o_start + (size_t)N * 4);

  // FULL layout
  size_t o_opay = al(o_cbuf + (size_t)E * 8);
  size_t o_xq4 = al(o_opay + (size_t)E * 8);
  size_t o_xq8f = al(o_xq4 + (size_t)N * 32);
  size_t need_full = o_xq8f + (size_t)N * 64;
  // COMPAT layout
  size_t o_order_c = al(o_cbuf + (size_t)E * 4);
  size_t o_xq8c = al(o_order_c + (size_t)E * 4);
  size_t need_compat = o_xq8c + (size_t)N * 64;

  int mode;
  if (ws_size >= need_full && E < (1 << 24) && N < (1 << 24)) mode = 2;
  else if (ws_size >= need_compat && E < (1 << 24)) mode = 1;
  else mode = 0;

  unsigned* head = (unsigned*)ws;
  unsigned* slot_ehi = (unsigned*)(ws + o_sehi);
  unsigned* slot_elo = (unsigned*)(ws + o_selo);
  unsigned* slot_ohi = (unsigned*)(ws + o_sohi);
  unsigned* slot_olo = (unsigned*)(ws + o_solo);
  unsigned* ccnt = (unsigned*)(ws + o_ccnt);
  unsigned* cstart = (unsigned*)(ws + o_cstart);
  unsigned* bwrite = (unsigned*)(ws + o_bwrite);
  unsigned char* msk = (unsigned char*)(ws + o_msk);
  float* rowmax = (float*)(ws + o_rowmax);
  unsigned* cnt = (unsigned*)(ws + o_cnt);
  unsigned* start = (unsigned*)(ws + o_start);
  unsigned long long* cbuf64 = (unsigned long long*)(ws + o_cbuf);
  unsigned* cbuf32 = (unsigned*)(ws + o_cbuf);
  unsigned long long* opay = (unsigned long long*)(ws + o_opay);
  unsigned* order32 = (unsigned*)(ws + o_order_c);
  unsigned char* xq4 = (unsigned char*)(ws + o_xq4);
  signed char* xq8 = (signed char*)(ws + ((mode == 2) ? o_xq8f : o_xq8c));

  int rowBlocks = (N + 3) / 4;
  int nbp = (E + BP_CHUNK - 1) / BP_CHUNK;
  int full = (mode == 2);

  k_zero<<<8, 256, 0, stream>>>(head, (int)(o_cstart / 4));
  k_detect<<<256, 256, 0, stream>>>((const unsigned char*)mraw, head, N);
  k_rowmax_canon<<<rowBlocks, 256, 0, stream>>>(x, mraw, head, rowmax, msk, N);
  k_edge_hist<<<256, 256, 0, stream>>>(dst, ccnt, E, NB, bsh, vec);
  k_cscan<<<1, 256, 0, stream>>>(ccnt, cstart, bwrite, NB);
  k_binplace<<<nbp, 256, 0, stream>>>(src, dst, msk, rowmax, bwrite, cbuf64, cbuf32,
                                      slot_ehi, slot_elo, E, NB, bsh, full, vec);
  k_scales<<<1, 256, 0, stream>>>(head, slot_ehi, slot_elo, 0);
  if (mode >= 1)
    k_quant48<<<rowBlocks, 256, 0, stream>>>(x, xq8, xq4, msk, head, N, mode);
  k_finesort<<<NB, 256, 0, stream>>>(cbuf64, cbuf32, cstart, opay, order32,
                                     cnt, start, N, bsh, full);
  if (mode >= 1) {
    k_aggr_small<<<(N + 15) / 16, 256, 0, stream>>>(xq8, xq4, opay, order32, src, msk,
                                                    start, cnt, head,
                                                    slot_ohi, slot_olo, out, N, mode);
    k_aggr_wave<<<rowBlocks, 256, 0, stream>>>(xq8, xq4, x, opay, order32, src, msk,
                                               start, cnt, head,
                                               slot_ohi, slot_olo, out, N, mode, 1);
  } else {
    k_aggr_wave<<<rowBlocks, 256, 0, stream>>>(xq8, xq4, x, opay, order32, src, msk,
                                               start, cnt, head,
                                               slot_ohi, slot_olo, out, N, mode, 0);
  }
  k_scales<<<1, 256, 0, stream>>>(head, slot_ohi, slot_olo, 1);
  k_quant_rows<<<rowBlocks, 256, 0, stream>>>(out, out, msk, head, N);
}

// Round 10
// 212.964 us; speedup vs baseline: 1.1147x; 1.0603x over previous
//
#include <hip/hip_runtime.h>

// head u32 words: 0:c0 1:c123 | hf[6]=shi_msg hf[7]=slo_msg hf[8]=shi_out hf[9]=slo_out
//                 11: nB (count of d>16 nodes, filled by finesort)
// FULL (mode 2): binplace packs u64 (local<<56)|(src<<32)|(msk<<24)|e ; finesort -> opay u64;
//   lo rows 4-bit plane xq4 (N*32 B), hi rows int8 xq8 (N*64 B).
// COMPAT (mode 1): u32 cbuf/order, xq8 for all rows, aggr gathers src/msk.
// RAW (mode 0): u32 cbuf/order, aggr quantizes from x on the fly.
// Constraints: E < 2^24, N < 2^24, bsh <= 8.

#define BP_CHUNK 4096
#define FS_CAP 2560

__global__ void k_zero(unsigned* p, int n) {
  int i = blockIdx.x * blockDim.x + threadIdx.x;
  for (; i < n; i += gridDim.x * blockDim.x) p[i] = 0u;
}

// Sniff mask dtype from raw bytes (reads only N bytes, safe for u8/i32/f32).
__global__ void k_detect(const unsigned char* m, unsigned* head, int nbytes) {
  int i = blockIdx.x * blockDim.x + threadIdx.x;
  int c0 = 0, c123 = 0;
  for (; i < nbytes; i += gridDim.x * blockDim.x) {
    unsigned char b = m[i];
    if (b) { if ((i & 3) == 0) c0++; else c123++; }
  }
  for (int o = 32; o; o >>= 1) { c0 += __shfl_xor(c0, o); c123 += __shfl_xor(c123, o); }
  if ((threadIdx.x & 63) == 0) {
    if (c0)   atomicAdd(&head[0], (unsigned)c0);
    if (c123) atomicAdd(&head[1], (unsigned)c123);
  }
}

// Canonicalize mask to u8 (thread per node) + rowmax (wave per node).
__global__ void k_rowmax_canon(const float* x, const void* mraw, const unsigned* head,
                               float* rowmax, unsigned char* msk, int N) {
  int gid = blockIdx.x * blockDim.x + threadIdx.x;
  if (gid < N) {
    unsigned c0 = head[0], c123 = head[1];
    int mode = (c123 == 0u) ? 1 : ((c0 == 0u) ? 2 : 0);
    unsigned char v;
    if (mode == 0)      v = (((const unsigned char*)mraw)[gid] != 0);
    else if (mode == 1) v = (((const int*)mraw)[gid] != 0);
    else                v = (((const float*)mraw)[gid] != 0.0f);
    msk[gid] = v;
  }
  int w = gid >> 6;
  int lane = threadIdx.x & 63;
  if (w >= N) return;
  float v = fabsf(x[(size_t)w * 64 + lane]);
  for (int o = 32; o; o >>= 1) v = fmaxf(v, __shfl_xor(v, o));
  if (lane == 0) rowmax[w] = v;
}

// Coarse histogram of dst>>bsh in LDS (vec4 reads), one global flush per block.
__global__ void k_edge_hist(const int* dst, unsigned* ccnt, int E, int NB, int bsh, int vec) {
  __shared__ unsigned h[1024];
  for (int i = threadIdx.x; i < NB; i += 256) h[i] = 0u;
  __syncthreads();
  int tid = blockIdx.x * blockDim.x + threadIdx.x;
  int st = gridDim.x * blockDim.x;
  int E4 = vec ? (E >> 2) : 0;
  const int4* d4 = (const int4*)dst;
  for (int i = tid; i < E4; i += st) {
    int4 v = d4[i];
    atomicAdd(&h[((unsigned)v.x) >> bsh], 1u);
    atomicAdd(&h[((unsigned)v.y) >> bsh], 1u);
    atomicAdd(&h[((unsigned)v.z) >> bsh], 1u);
    atomicAdd(&h[((unsigned)v.w) >> bsh], 1u);
  }
  for (int e = E4 * 4 + tid; e < E; e += st)
    atomicAdd(&h[((unsigned)dst[e]) >> bsh], 1u);
  __syncthreads();
  for (int i = threadIdx.x; i < NB; i += 256)
    if (h[i]) atomicAdd(&ccnt[i], h[i]);
}

// One-block exclusive scan of ccnt[NB] -> cstart[NB+1]; also init bwrite=cstart.
__global__ void k_cscan(const unsigned* ccnt, unsigned* cstart, unsigned* bwrite, int NB) {
  __shared__ unsigned sh[1024];
  int t = threadIdx.x;
  for (int i = t; i < 1024; i += 256) sh[i] = (i < NB) ? ccnt[i] : 0u;
  __syncthreads();
  for (int off = 1; off < 1024; off <<= 1) {
    unsigned v[4];
    #pragma unroll
    for (int j = 0; j < 4; j++) { int i = t + j * 256; v[j] = (i >= off) ? sh[i - off] : 0u; }
    __syncthreads();
    #pragma unroll
    for (int j = 0; j < 4; j++) { int i = t + j * 256; sh[i] += v[j]; }
    __syncthreads();
  }
  for (int i = t; i < 1024; i += 256) {
    unsigned excl = (i == 0) ? 0u : sh[i - 1];
    if (i < NB) { cstart[i] = excl; bwrite[i] = excl; }
    if (i == NB - 1) cstart[NB] = sh[i];
  }
}

// Coarse binning: LDS hist -> bulk reservation -> scatter (u64 in FULL mode,
// carrying src+msk so aggregation never re-gathers them). Also per-edge class
// amax of rowmax[src] into spread slots.
__global__ void k_binplace(const int* src, const int* dst, const unsigned char* msk,
                           const float* rowmax, unsigned* bwrite,
                           unsigned long long* cbuf64, unsigned* cbuf32,
                           unsigned* slot_ehi, unsigned* slot_elo,
                           int E, int NB, int bsh, int full, int vec) {
  __shared__ unsigned h[1024], base[1024];
  __shared__ float sh_hi[4], sh_lo[4];
  int cbase = blockIdx.x * BP_CHUNK;
  int cend = cbase + BP_CHUNK; if (cend > E) cend = E;
  int n = cend - cbase;
  int n4 = vec ? (n >> 2) : 0;
  for (int i = threadIdx.x; i < NB; i += 256) h[i] = 0u;
  __syncthreads();
  const int4* d4 = (const int4*)(dst + cbase);
  const int4* s4 = (const int4*)(src + cbase);
  for (int i = threadIdx.x; i < n4; i += 256) {
    int4 v = d4[i];
    atomicAdd(&h[((unsigned)v.x) >> bsh], 1u);
    atomicAdd(&h[((unsigned)v.y) >> bsh], 1u);
    atomicAdd(&h[((unsigned)v.z) >> bsh], 1u);
    atomicAdd(&h[((unsigned)v.w) >> bsh], 1u);
  }
  for (int e = cbase + n4 * 4 + threadIdx.x; e < cend; e += 256)
    atomicAdd(&h[((unsigned)dst[e]) >> bsh], 1u);
  __syncthreads();
  for (int i = threadIdx.x; i < NB; i += 256) {
    unsigned c = h[i];
    base[i] = c ? atomicAdd(&bwrite[i], c) : 0u;
    h[i] = 0u;  // reuse as cursor
  }
  __syncthreads();
  unsigned lmask = (1u << bsh) - 1u;
  float hi = 0.0f, lo = 0.0f;
  for (int i = threadIdx.x; i < n4; i += 256) {
    int4 dv = d4[i]; int4 sv = s4[i];
    int e0 = cbase + i * 4;
    int dd[4] = {dv.x, dv.y, dv.z, dv.w};
    int ss[4] = {sv.x, sv.y, sv.z, sv.w};
    #pragma unroll
    for (int j = 0; j < 4; j++) {
      int d = dd[j], s = ss[j];
      unsigned mk = msk[s];
      float r = rowmax[s];
      if (mk) hi = fmaxf(hi, r); else lo = fmaxf(lo, r);
      unsigned b = (unsigned)d >> bsh;
      unsigned pos = base[b] + atomicAdd(&h[b], 1u);
      if (full)
        cbuf64[pos] = ((unsigned long long)(((((unsigned)d) & lmask) << 24) | (unsigned)s) << 32)
                      | ((mk << 24) | (unsigned)(e0 + j));
      else
        cbuf32[pos] = ((((unsigned)d) & lmask) << 24) | (unsigned)(e0 + j);
    }
  }
  for (int e = cbase + n4 * 4 + threadIdx.x; e < cend; e += 256) {
    int d = dst[e], s = src[e];
    unsigned mk = msk[s];
    float r = rowmax[s];
    if (mk) hi = fmaxf(hi, r); else lo = fmaxf(lo, r);
    unsigned b = (unsigned)d >> bsh;
    unsigned pos = base[b] + atomicAdd(&h[b], 1u);
    if (full)
      cbuf64[pos] = ((unsigned long long)(((((unsigned)d) & lmask) << 24) | (unsigned)s) << 32)
                    | ((mk << 24) | (unsigned)e);
    else
      cbuf32[pos] = ((((unsigned)d) & lmask) << 24) | (unsigned)e;
  }
  for (int o = 32; o; o >>= 1) { hi = fmaxf(hi, __shfl_xor(hi, o)); lo = fmaxf(lo, __shfl_xor(lo, o)); }
  int wid = threadIdx.x >> 6, lane = threadIdx.x & 63;
  if (lane == 0) { sh_hi[wid] = hi; sh_lo[wid] = lo; }
  __syncthreads();
  if (threadIdx.x == 0) {
    float hh = fmaxf(fmaxf(sh_hi[0], sh_hi[1]), fmaxf(sh_hi[2], sh_hi[3]));
    float ll = fmaxf(fmaxf(sh_lo[0], sh_lo[1]), fmaxf(sh_lo[2], sh_lo[3]));
    atomicMax(&slot_ehi[blockIdx.x & 255], __float_as_uint(hh));
    atomicMax(&slot_elo[blockIdx.x & 255], __float_as_uint(ll));
  }
}

// One block per coarse bucket: stage entries in LDS (single global read),
// per-node counts + scan, write cnt/start, scatter within bucket region.
// Also appends d>16 nodes to nodeB (one global atomicAdd per block).
// Unstaged fallback for adversarial buckets (> FS_CAP entries).
__global__ void k_finesort(const unsigned long long* cbuf64, const unsigned* cbuf32,
                           const unsigned* cstart,
                           unsigned long long* opay, unsigned* order32,
                           unsigned* cnt, unsigned* start, unsigned* head,
                           unsigned* nodeB, int N, int bsh, int full) {
  __shared__ unsigned h[256], lofs[256], cur[256];
  __shared__ unsigned long long ent[FS_CAP];
  __shared__ unsigned bigcnt, bigbase;
  int b = blockIdx.x;
  unsigned rbase = cstart[b], rend = cstart[b + 1];
  unsigned n = rend - rbase;
  int t = threadIdx.x;
  h[t] = 0u;
  if (t == 0) bigcnt = 0u;
  __syncthreads();
  bool staged = (n <= (unsigned)FS_CAP);
  if (staged) {
    for (unsigned j = (unsigned)t; j < n; j += 256) {
      unsigned long long v = full ? cbuf64[rbase + j]
                                  : (unsigned long long)cbuf32[rbase + j];
      ent[j] = v;
      unsigned loc = full ? (unsigned)(v >> 56) : (((unsigned)v) >> 24);
      atomicAdd(&h[loc], 1u);
    }
  } else {
    for (unsigned j = rbase + (unsigned)t; j < rend; j += 256) {
      unsigned loc = full ? (unsigned)(cbuf64[j] >> 56) : (cbuf32[j] >> 24);
      atomicAdd(&h[loc], 1u);
    }
  }
  __syncthreads();
  lofs[t] = h[t];
  __syncthreads();
  for (int off = 1; off < 256; off <<= 1) {
    unsigned v = (t >= off) ? lofs[t - off] : 0u;
    __syncthreads();
    lofs[t] += v;
    __syncthreads();
  }
  unsigned dcount = h[t];
  unsigned excl = lofs[t] - dcount;
  cur[t] = excl;
  int nper = 1 << bsh;
  int node = (b << bsh) + t;
  bool valid = (t < nper) && (node < N);
  if (valid) { cnt[node] = dcount; start[node] = rbase + excl; }
  // collect big nodes (d>16) for the wave-aggregation kernel
  unsigned myidx = 0u;
  bool big = valid && dcount > 16u;
  if (big) myidx = atomicAdd(&bigcnt, 1u);
  __syncthreads();
  if (t == 0 && bigcnt) bigbase = atomicAdd(&head[11], bigcnt);
  __syncthreads();
  if (big) nodeB[bigbase + myidx] = (unsigned)node;
  if (staged) {
    for (unsigned j = (unsigned)t; j < n; j += 256) {
      unsigned long long v = ent[j];
      unsigned loc = full ? (unsigned)(v >> 56) : (((unsigned)v) >> 24);
      unsigned pos = rbase + atomicAdd(&cur[loc], 1u);
      if (full) opay[pos] = v; else order32[pos] = (unsigned)v & 0x00FFFFFFu;
    }
  } else {
    for (unsigned j = rbase + (unsigned)t; j < rend; j += 256) {
      if (full) {
        unsigned long long v = cbuf64[j];
        unsigned pos = rbase + atomicAdd(&cur[(unsigned)(v >> 56)], 1u);
        opay[pos] = v;
      } else {
        unsigned v = cbuf32[j];
        unsigned pos = rbase + atomicAdd(&cur[v >> 24], 1u);
        order32[pos] = v & 0x00FFFFFFu;
      }
    }
  }
  __syncthreads();
  if (valid && dcount > 64u) {  // practically never; correctness fallback
    unsigned s0 = rbase + excl;
    if (full) {
      for (unsigned i = 1; i < dcount; i++) {
        unsigned long long key = opay[s0 + i];
        unsigned kk = (unsigned)key & 0xFFFFFFu;
        int j = (int)i - 1;
        while (j >= 0 && ((unsigned)opay[s0 + j] & 0xFFFFFFu) > kk) {
          opay[s0 + j + 1] = opay[s0 + j]; j--;
        }
        opay[s0 + (unsigned)(j + 1)] = key;
      }
    } else {
      for (unsigned i = 1; i < dcount; i++) {
        unsigned key = order32[s0 + i];
        int j = (int)i - 1;
        while (j >= 0 && order32[s0 + j] > key) { order32[s0 + j + 1] = order32[s0 + j]; j--; }
        order32[s0 + (unsigned)(j + 1)] = key;
      }
    }
  }
}

// Reduce 256-slot amax arrays -> scales in head. which=0: msg; which=1: out.
__global__ void k_scales(unsigned* head, const unsigned* shi, const unsigned* slo, int which) {
  __shared__ unsigned smh[256], sml[256];
  int t = threadIdx.x;
  smh[t] = shi[t]; sml[t] = slo[t];
  __syncthreads();
  for (int off = 128; off > 0; off >>= 1) {
    if (t < off) {
      smh[t] = smh[t] > smh[t + off] ? smh[t] : smh[t + off];
      sml[t] = sml[t] > sml[t + off] ? sml[t] : sml[t + off];
    }
    __syncthreads();
  }
  if (t == 0) {
    float* hf = (float*)head;
    float ah = __uint_as_float(smh[0]);
    float al = __uint_as_float(sml[0]);
    hf[6 + which * 2]     = __fdiv_rn(fmaxf(ah, 1e-8f), 127.0f);
    hf[6 + which * 2 + 1] = __fdiv_rn(fmaxf(al, 1e-8f), 7.0f);
  }
}

// Quantize rows. mode2: hi rows -> int8 xq8; lo rows -> packed 4-bit xq4
// (code+8 in [1,15], bit-exact nibble roundtrip). mode1: int8 for all.
__global__ void k_quant48(const float* x, signed char* xq8, unsigned char* xq4,
                          const unsigned char* msk, const unsigned* head,
                          int N, int mode) {
  int w = (int)((blockIdx.x * blockDim.x + threadIdx.x) >> 6);
  int lane = threadIdx.x & 63;
  if (w >= N) return;
  const float* hf = (const float*)head;
  bool m = msk[w] != 0;
  float sc = m ? hf[6] : hf[7];
  float qm = m ? 127.0f : 7.0f;
  float t = __fdiv_rn(x[(size_t)w * 64 + lane], sc);
  t = fminf(fmaxf(t, -qm), qm);
  t = rintf(t);
  if (mode == 2 && !m) {
    int nib = (int)t + 8;  // 1..15
    int other = __shfl_xor(nib, 1);
    if (!(lane & 1)) xq4[(size_t)w * 32 + (lane >> 1)] = (unsigned char)(nib | (other << 4));
  } else {
    xq8[(size_t)w * 64 + lane] = (signed char)t;
  }
}

// Final fake-quant of output rows (in-place, float).
__global__ void k_quant_rows(const float* in, float* out, const unsigned char* msk,
                             const unsigned* head, int N) {
  int w = (int)((blockIdx.x * blockDim.x + threadIdx.x) >> 6);
  int lane = threadIdx.x & 63;
  if (w >= N) return;
  const float* hf = (const float*)head;
  bool m = msk[w] != 0;
  float sc = m ? hf[8] : hf[9];
  float qm = m ? 127.0f : 7.0f;
  float v = in[(size_t)w * 64 + lane];
  float t = __fdiv_rn(v, sc);
  t = fminf(fmaxf(t, -qm), qm);
  t = rintf(t);
  out[(size_t)w * 64 + lane] = __fmul_rn(sc, t);
}

// Small nodes (d<=16), direct node indexing: 16-lane group per node, lane =
// 4 features, bitonic-16 order restore, 16 gathers in flight. Register-lean.
__global__ void k_aggr_small(const signed char* xq8, const unsigned char* xq4,
                             const unsigned long long* opay, const unsigned* order32,
                             const int* src, const unsigned char* msk,
                             const unsigned* start, const unsigned* cnt,
                             const unsigned* head,
                             unsigned* slot_ohi, unsigned* slot_olo,
                             float* out, int N, int mode) {
  int t = blockIdx.x * blockDim.x + threadIdx.x;
  int node = t >> 4;
  int g = threadIdx.x & 15;
  if (node >= N) return;
  unsigned d = cnt[node];
  if (d > 16u) return;
  unsigned s0 = start[node];
  const float* hf = (const float*)head;
  float shi = hf[6], slo = hf[7];

  unsigned key = 0xFFFFFFFFu, pay = 0u;
  if ((unsigned)g < d) {
    if (mode == 2) {
      unsigned long long v = opay[s0 + (unsigned)g];
      key = (unsigned)v & 0xFFFFFFu;
      pay = ((unsigned)(v >> 32) & 0xFFFFFFu) | (((unsigned)(v >> 24) & 1u) << 31);
    } else {
      unsigned e = order32[s0 + (unsigned)g];
      int s = src[e];
      key = e;
      pay = (unsigned)s | (((unsigned)msk[s]) << 31);
    }
  }
  #pragma unroll
  for (int size = 2; size <= 16; size <<= 1) {
    #pragma unroll
    for (int stride = size >> 1; stride > 0; stride >>= 1) {
      unsigned ok = __shfl_xor(key, stride);
      unsigned op = __shfl_xor(pay, stride);
      bool up = ((g & size) == 0);
      bool keepMin = (((g & stride) == 0) == up);
      bool sw = keepMin ? (ok < key) : (ok > key);
      if (sw) { key = ok; pay = op; }
    }
  }
  int gbase = threadIdx.x & ~15;
  unsigned wv[16];
  #pragma unroll
  for (int j = 0; j < 16; j++) {
    int sl = gbase + ((j < (int)d) ? j : 0);
    unsigned p = __shfl(pay, sl);
    unsigned sn = p & 0x7FFFFFFFu;
    if (mode == 2 && !(p >> 31))
      wv[j] = *(const unsigned short*)(xq4 + (size_t)sn * 32 + g * 2);
    else
      wv[j] = *(const unsigned*)(xq8 + (size_t)sn * 64 + g * 4);
  }
  float acc0 = 0.0f, acc1 = 0.0f, acc2 = 0.0f, acc3 = 0.0f;
  #pragma unroll
  for (int j = 0; j < 16; j++) {
    int sl = gbase + ((j < (int)d) ? j : 0);
    unsigned p = __shfl(pay, sl);
    bool hi = (p >> 31) != 0;
    float s = (j < (int)d) ? (hi ? shi : slo) : 0.0f;  // 0-scale pads: +-0 adds
    unsigned w = wv[j];
    if (mode == 2 && !hi) {
      acc0 = __fadd_rn(acc0, __fmul_rn(s, (float)((int)(w & 15) - 8)));
      acc1 = __fadd_rn(acc1, __fmul_rn(s, (float)((int)((w >> 4) & 15) - 8)));
      acc2 = __fadd_rn(acc2, __fmul_rn(s, (float)((int)((w >> 8) & 15) - 8)));
      acc3 = __fadd_rn(acc3, __fmul_rn(s, (float)((int)((w >> 12) & 15) - 8)));
    } else {
      acc0 = __fadd_rn(acc0, __fmul_rn(s, (float)(int)(signed char)(w & 0xFF)));
      acc1 = __fadd_rn(acc1, __fmul_rn(s, (float)(int)(signed char)((w >> 8) & 0xFF)));
      acc2 = __fadd_rn(acc2, __fmul_rn(s, (float)(int)(signed char)((w >> 16) & 0xFF)));
      acc3 = __fadd_rn(acc3, __fmul_rn(s, (float)(int)(signed char)((w >> 24) & 0xFF)));
    }
  }
  float4 o4; o4.x = acc0; o4.y = acc1; o4.z = acc2; o4.w = acc3;
  *(float4*)(out + (size_t)node * 64 + g * 4) = o4;

  float a = fmaxf(fmaxf(fabsf(acc0), fabsf(acc1)), fmaxf(fabsf(acc2), fabsf(acc3)));
  #pragma unroll
  for (int o = 8; o; o >>= 1) a = fmaxf(a, __shfl_xor(a, o));
  if (g == 0) {
    unsigned* sl = msk[node] ? slot_ohi : slot_olo;
    atomicMax(&sl[node & 255], __float_as_uint(a));
  }
}

// Wave-per-node path: big-node list (use_list=1) or all nodes (mode0).
__global__ void k_aggr_wave(const signed char* xq8, const unsigned char* xq4,
                            const float* x,
                            const unsigned long long* opay, const unsigned* order32,
                            const int* src, const unsigned char* msk,
                            const unsigned* start, const unsigned* cnt,
                            const unsigned* head, const unsigned* nodeB,
                            unsigned* slot_ohi, unsigned* slot_olo,
                            float* out, int N, int mode, int use_list) {
  int w = (int)((blockIdx.x * blockDim.x + threadIdx.x) >> 6);
  int lane = threadIdx.x & 63;
  int node;
  if (use_list) {
    unsigned nB = head[11];
    if ((unsigned)w >= nB) return;
    node = (int)nodeB[w];
  } else {
    if (w >= N) return;
    node = w;
  }
  unsigned d = cnt[node];
  unsigned s0 = start[node];
  const float* hf = (const float*)head;
  float shi = hf[6], slo = hf[7];
  float acc = 0.0f;

  if (d <= 64u) {
    unsigned key = 0xFFFFFFFFu, pay = 0u;
    if ((unsigned)lane < d) {
      if (mode == 2) {
        unsigned long long v = opay[s0 + (unsigned)lane];
        key = (unsigned)v & 0xFFFFFFu;
        pay = ((unsigned)(v >> 32) & 0xFFFFFFu) | (((unsigned)(v >> 24) & 1u) << 31);
      } else {
        unsigned e = order32[s0 + (unsigned)lane];
        int s = src[e];
        key = e;
        pay = (unsigned)s | (((unsigned)msk[s]) << 31);
      }
    }
    #pragma unroll
    for (int size = 2; size <= 32; size <<= 1) {
      #pragma unroll
      for (int stride = size >> 1; stride > 0; stride >>= 1) {
        unsigned ok = __shfl_xor(key, stride);
        unsigned op = __shfl_xor(pay, stride);
        bool up = ((lane & size) == 0);
        bool keepMin = (((lane & stride) == 0) == up);
        bool sw = keepMin ? (ok < key) : (ok > key);
        if (sw) { key = ok; pay = op; }
      }
    }
    if (d > 32u) {
      #pragma unroll
      for (int stride = 32; stride > 0; stride >>= 1) {
        unsigned ok = __shfl_xor(key, stride);
        unsigned op = __shfl_xor(pay, stride);
        bool keepMin = ((lane & stride) == 0);
        bool sw = keepMin ? (ok < key) : (ok > key);
        if (sw) { key = ok; pay = op; }
      }
    }
    for (unsigned kb = 0; kb < d; kb += 16) {
      float vv[16];
      #pragma unroll
      for (int j = 0; j < 16; j++) {
        unsigned kk = kb + (unsigned)j;
        int sl = (int)(kk < d ? kk : 0u);
        unsigned p = __shfl(pay, sl);
        float sc = (p >> 31) ? shi : slo;
        float scm = (kk < d) ? sc : 0.0f;
        unsigned sn = p & 0x7FFFFFFFu;
        float q;
        if (mode == 2) {
          if (p >> 31) {
            q = (float)xq8[(size_t)sn * 64 + lane];
          } else {
            unsigned bb = xq4[(size_t)sn * 32 + (lane >> 1)];
            int nib = (lane & 1) ? (int)(bb >> 4) : (int)(bb & 15);
            q = (float)(nib - 8);
          }
        } else if (mode == 1) {
          q = (float)xq8[(size_t)sn * 64 + lane];
        } else {
          float qm = (p >> 31) ? 127.0f : 7.0f;
          float tq = __fdiv_rn(x[(size_t)sn * 64 + lane], sc);
          tq = fminf(fmaxf(tq, -qm), qm);
          q = rintf(tq);
        }
        vv[j] = __fmul_rn(scm, q);
      }
      #pragma unroll
      for (int j = 0; j < 16; j++) acc = __fadd_rn(acc, vv[j]);
    }
  } else {
    for (unsigned k = 0; k < d; k++) {
      unsigned sn; bool m;
      if (mode == 2) {
        unsigned long long v = opay[s0 + k];
        sn = (unsigned)(v >> 32) & 0xFFFFFFu;
        m = ((v >> 24) & 1ull) != 0;
      } else {
        unsigned e = order32[s0 + k];
        sn = (unsigned)src[e];
        m = msk[sn] != 0;
      }
      float sc = m ? shi : slo;
      float q;
      if (mode == 2) {
        if (m) {
          q = (float)xq8[(size_t)sn * 64 + lane];
        } else {
          unsigned bb = xq4[(size_t)sn * 32 + (lane >> 1)];
          int nib = (lane & 1) ? (int)(bb >> 4) : (int)(bb & 15);
          q = (float)(nib - 8);
        }
      } else if (mode == 1) {
        q = (float)xq8[(size_t)sn * 64 + lane];
      } else {
        float qm = m ? 127.0f : 7.0f;
        float tq = __fdiv_rn(x[(size_t)sn * 64 + lane], sc);
        tq = fminf(fmaxf(tq, -qm), qm);
        q = rintf(tq);
      }
      acc = __fadd_rn(acc, __fmul_rn(sc, q));
    }
  }

  out[(size_t)node * 64 + lane] = acc;

  float a = fabsf(acc);
  for (int o = 32; o; o >>= 1) a = fmaxf(a, __shfl_xor(a, o));
  if (lane == 0) {
    unsigned* sl = (msk[node] != 0) ? slot_ohi : slot_olo;
    atomicMax(&sl[node & 255], __float_as_uint(a));
  }
}

extern "C" void kernel_launch(void* const* d_in, const int* in_sizes, int n_in,
                              void* d_out, int out_size, void* d_ws, size_t ws_size,
                              hipStream_t stream) {
  const float* x = (const float*)d_in[0];
  const int* ei = (const int*)d_in[1];
  const void* mraw = d_in[2];
  int N = in_sizes[2];
  int E = in_sizes[1] / 2;
  const int* src = ei;
  const int* dst = ei + E;
  float* out = (float*)d_out;

  int bsh = 7;
  while ((((N - 1) >> bsh) + 1) > 1024 && bsh < 8) bsh++;
  int NB = ((N - 1) >> bsh) + 1;
  int vec = (((uintptr_t)src & 15) == 0) && (((uintptr_t)dst & 15) == 0) && ((E & 3) == 0);

  char* ws = (char*)d_ws;
  auto al = [](size_t v) { return ((v + 255) / 256) * 256; };
  size_t o_sehi = 256, o_selo = 1280, o_sohi = 2304, o_solo = 3328;
  size_t o_ccnt = 4352;
  size_t o_cstart = al(o_ccnt + (size_t)(NB + 1) * 4);
  size_t o_bwrite = al(o_cstart + (size_t)(NB + 1) * 4);
  size_t o_msk = al(o_bwrite + (size_t)NB * 4);
  size_t o_rowmax = al(o_msk + (size_t)N);
  size_t o_cnt = o_rowmax + (size_t)N * 4;
  size_t o_start = o_cnt + (size_t)N * 4;
  size_t o_nodeB = o_start + (size_t)N * 4;
  size_t o_cbuf = al(o_nodeB + (size_t)N * 4);

  // FULL layout
  size_t o_opay = al(o_cbuf + (size_t)E * 8);
  size_t o_xq4 = al(o_opay + (size_t)E * 8);
  size_t o_xq8f = al(o_xq4 + (size_t)N * 32);
  size_t need_full = o_xq8f + (size_t)N * 64;
  // COMPAT layout
  size_t o_order_c = al(o_cbuf + (size_t)E * 4);
  size_t o_xq8c = al(o_order_c + (size_t)E * 4);
  size_t need_compat = o_xq8c + (size_t)N * 64;

  int mode;
  if (ws_size >= need_full && E < (1 << 24) && N < (1 << 24)) mode = 2;
  else if (ws_size >= need_compat && E < (1 << 24)) mode = 1;
  else mode = 0;

  unsigned* head = (unsigned*)ws;
  unsigned* slot_ehi = (unsigned*)(ws + o_sehi);
  unsigned* slot_elo = (unsigned*)(ws + o_selo);
  unsigned* slot_ohi = (unsigned*)(ws + o_sohi);
  unsigned* slot_olo = (unsigned*)(ws + o_solo);
  unsigned* ccnt = (unsigned*)(ws + o_ccnt);
  unsigned* cstart = (unsigned*)(ws + o_cstart);
  unsigned* bwrite = (unsigned*)(ws + o_bwrite);
  unsigned char* msk = (unsigned char*)(ws + o_msk);
  float* rowmax = (float*)(ws + o_rowmax);
  unsigned* cnt = (unsigned*)(ws + o_cnt);
  unsigned* start = (unsigned*)(ws + o_start);
  unsigned* nodeB = (unsigned*)(ws + o_nodeB);
  unsigned long long* cbuf64 = (unsigned long long*)(ws + o_cbuf);
  unsigned* cbuf32 = (unsigned*)(ws + o_cbuf);
  unsigned long long* opay = (unsigned long long*)(ws + o_opay);
  unsigned* order32 = (unsigned*)(ws + o_order_c);
  unsigned char* xq4 = (unsigned char*)(ws + o_xq4);
  signed char* xq8 = (signed char*)(ws + ((mode == 2) ? o_xq8f : o_xq8c));

  int rowBlocks = (N + 3) / 4;
  int nbp = (E + BP_CHUNK - 1) / BP_CHUNK;
  int full = (mode == 2);

  k_zero<<<8, 256, 0, stream>>>(head, (int)(o_cstart / 4));
  k_detect<<<256, 256, 0, stream>>>((const unsigned char*)mraw, head, N);
  k_rowmax_canon<<<rowBlocks, 256, 0, stream>>>(x, mraw, head, rowmax, msk, N);
  k_edge_hist<<<256, 256, 0, stream>>>(dst, ccnt, E, NB, bsh, vec);
  k_cscan<<<1, 256, 0, stream>>>(ccnt, cstart, bwrite, NB);
  k_binplace<<<nbp, 256, 0, stream>>>(src, dst, msk, rowmax, bwrite, cbuf64, cbuf32,
                                      slot_ehi, slot_elo, E, NB, bsh, full, vec);
  k_scales<<<1, 256, 0, stream>>>(head, slot_ehi, slot_elo, 0);
  if (mode >= 1)
    k_quant48<<<rowBlocks, 256, 0, stream>>>(x, xq8, xq4, msk, head, N, mode);
  k_finesort<<<NB, 256, 0, stream>>>(cbuf64, cbuf32, cstart, opay, order32,
                                     cnt, start, head, nodeB, N, bsh, full);
  if (mode >= 1) {
    k_aggr_small<<<(N + 15) / 16, 256, 0, stream>>>(xq8, xq4, opay, order32, src, msk,
                                                    start, cnt, head,
                                                    slot_ohi, slot_olo, out, N, mode);
    k_aggr_wave<<<rowBlocks, 256, 0, stream>>>(xq8, xq4, x, opay, order32, src, msk,
                                               start, cnt, head, nodeB,
                                               slot_ohi, slot_olo, out, N, mode, 1);
  } else {
    k_aggr_wave<<<rowBlocks, 256, 0, stream>>>(xq8, xq4, x, opay, order32, src, msk,
                                               start, cnt, head, nodeB,
                                               slot_ohi, slot_olo, out, N, mode, 0);
  }
  k_scales<<<1, 256, 0, stream>>>(head, slot_ohi, slot_olo, 1);
  k_quant_rows<<<rowBlocks, 256, 0, stream>>>(out, out, msk, head, N);
}

// Round 11
// 202.413 us; speedup vs baseline: 1.1728x; 1.0521x over previous
//
#include <hip/hip_runtime.h>

// head u32 words: 0:c0 1:c123 | hf[6]=shi_msg hf[7]=slo_msg hf[8]=shi_out hf[9]=slo_out
//                 11: nB (count of d>16 nodes, filled by finesort)
// FULL (mode 2): binplace packs u64 (local<<56)|(src<<32)|(msk<<24)|e ; finesort -> opay u64;
//   all rows int8 xq8 (N*64 B) -> uniform byte decode in aggregation.
// COMPAT (mode 1): u32 cbuf/order, xq8, aggr gathers src/msk.
// RAW (mode 0): u32 cbuf/order, aggr quantizes from x on the fly.
// rowmax[] carries msk in its sign bit (set by rowmax_canon, consumed by binplace).
// Constraints: E < 2^24, N < 2^24, bsh <= 8.

#define BP_CHUNK 4096
#define FS_CAP 2560

__global__ void k_zero(unsigned* p, int n) {
  int i = blockIdx.x * blockDim.x + threadIdx.x;
  for (; i < n; i += gridDim.x * blockDim.x) p[i] = 0u;
}

// Sniff mask dtype from raw bytes (reads only N bytes, safe for u8/i32/f32).
__global__ void k_detect(const unsigned char* m, unsigned* head, int nbytes) {
  int i = blockIdx.x * blockDim.x + threadIdx.x;
  int c0 = 0, c123 = 0;
  for (; i < nbytes; i += gridDim.x * blockDim.x) {
    unsigned char b = m[i];
    if (b) { if ((i & 3) == 0) c0++; else c123++; }
  }
  for (int o = 32; o; o >>= 1) { c0 += __shfl_xor(c0, o); c123 += __shfl_xor(c123, o); }
  if ((threadIdx.x & 63) == 0) {
    if (c0)   atomicAdd(&head[0], (unsigned)c0);
    if (c123) atomicAdd(&head[1], (unsigned)c123);
  }
}

__device__ __forceinline__ unsigned char mask_of(const void* mraw, unsigned c0,
                                                 unsigned c123, int i) {
  int mode = (c123 == 0u) ? 1 : ((c0 == 0u) ? 2 : 0);
  if (mode == 0)      return ((const unsigned char*)mraw)[i] != 0;
  else if (mode == 1) return ((const int*)mraw)[i] != 0;
  else                return ((const float*)mraw)[i] != 0.0f;
}

// Canonicalize mask to u8 (thread per node) + rowmax with msk packed in sign
// bit (wave per node; lane 0 re-derives msk for its node from mraw).
__global__ void k_rowmax_canon(const float* x, const void* mraw, const unsigned* head,
                               float* rowmax, unsigned char* msk, int N) {
  unsigned c0 = head[0], c123 = head[1];
  int gid = blockIdx.x * blockDim.x + threadIdx.x;
  if (gid < N) msk[gid] = mask_of(mraw, c0, c123, gid);
  int w = gid >> 6;
  int lane = threadIdx.x & 63;
  if (w >= N) return;
  float v = fabsf(x[(size_t)w * 64 + lane]);
  for (int o = 32; o; o >>= 1) v = fmaxf(v, __shfl_xor(v, o));
  if (lane == 0) {
    unsigned char m = mask_of(mraw, c0, c123, w);
    rowmax[w] = m ? -v : v;   // sign bit = mask class (works for v==0 via -0.0f)
  }
}

// Coarse histogram of dst>>bsh in LDS (vec4 reads), one global flush per block.
__global__ void k_edge_hist(const int* dst, unsigned* ccnt, int E, int NB, int bsh, int vec) {
  __shared__ unsigned h[1024];
  for (int i = threadIdx.x; i < NB; i += 256) h[i] = 0u;
  __syncthreads();
  int tid = blockIdx.x * blockDim.x + threadIdx.x;
  int st = gridDim.x * blockDim.x;
  int E4 = vec ? (E >> 2) : 0;
  const int4* d4 = (const int4*)dst;
  for (int i = tid; i < E4; i += st) {
    int4 v = d4[i];
    atomicAdd(&h[((unsigned)v.x) >> bsh], 1u);
    atomicAdd(&h[((unsigned)v.y) >> bsh], 1u);
    atomicAdd(&h[((unsigned)v.z) >> bsh], 1u);
    atomicAdd(&h[((unsigned)v.w) >> bsh], 1u);
  }
  for (int e = E4 * 4 + tid; e < E; e += st)
    atomicAdd(&h[((unsigned)dst[e]) >> bsh], 1u);
  __syncthreads();
  for (int i = threadIdx.x; i < NB; i += 256)
    if (h[i]) atomicAdd(&ccnt[i], h[i]);
}

// One-block exclusive scan of ccnt[NB] -> cstart[NB+1]; also init bwrite=cstart.
__global__ void k_cscan(const unsigned* ccnt, unsigned* cstart, unsigned* bwrite, int NB) {
  __shared__ unsigned sh[1024];
  int t = threadIdx.x;
  for (int i = t; i < 1024; i += 256) sh[i] = (i < NB) ? ccnt[i] : 0u;
  __syncthreads();
  for (int off = 1; off < 1024; off <<= 1) {
    unsigned v[4];
    #pragma unroll
    for (int j = 0; j < 4; j++) { int i = t + j * 256; v[j] = (i >= off) ? sh[i - off] : 0u; }
    __syncthreads();
    #pragma unroll
    for (int j = 0; j < 4; j++) { int i = t + j * 256; sh[i] += v[j]; }
    __syncthreads();
  }
  for (int i = t; i < 1024; i += 256) {
    unsigned excl = (i == 0) ? 0u : sh[i - 1];
    if (i < NB) { cstart[i] = excl; bwrite[i] = excl; }
    if (i == NB - 1) cstart[NB] = sh[i];
  }
}

// Coarse binning: LDS hist -> bulk reservation -> scatter (u64 in FULL mode,
// carrying src+msk so aggregation never re-gathers them). ONE gather per edge:
// rowmax[s] with msk in the sign bit.
__global__ void k_binplace(const int* src, const int* dst,
                           const float* rowmax, unsigned* bwrite,
                           unsigned long long* cbuf64, unsigned* cbuf32,
                           unsigned* slot_ehi, unsigned* slot_elo,
                           int E, int NB, int bsh, int full, int vec) {
  __shared__ unsigned h[1024], base[1024];
  __shared__ float sh_hi[4], sh_lo[4];
  int cbase = blockIdx.x * BP_CHUNK;
  int cend = cbase + BP_CHUNK; if (cend > E) cend = E;
  int n = cend - cbase;
  int n4 = vec ? (n >> 2) : 0;
  for (int i = threadIdx.x; i < NB; i += 256) h[i] = 0u;
  __syncthreads();
  const int4* d4 = (const int4*)(dst + cbase);
  const int4* s4 = (const int4*)(src + cbase);
  for (int i = threadIdx.x; i < n4; i += 256) {
    int4 v = d4[i];
    atomicAdd(&h[((unsigned)v.x) >> bsh], 1u);
    atomicAdd(&h[((unsigned)v.y) >> bsh], 1u);
    atomicAdd(&h[((unsigned)v.z) >> bsh], 1u);
    atomicAdd(&h[((unsigned)v.w) >> bsh], 1u);
  }
  for (int e = cbase + n4 * 4 + threadIdx.x; e < cend; e += 256)
    atomicAdd(&h[((unsigned)dst[e]) >> bsh], 1u);
  __syncthreads();
  for (int i = threadIdx.x; i < NB; i += 256) {
    unsigned c = h[i];
    base[i] = c ? atomicAdd(&bwrite[i], c) : 0u;
    h[i] = 0u;  // reuse as cursor
  }
  __syncthreads();
  unsigned lmask = (1u << bsh) - 1u;
  float hi = 0.0f, lo = 0.0f;
  for (int i = threadIdx.x; i < n4; i += 256) {
    int4 dv = d4[i]; int4 sv = s4[i];
    int e0 = cbase + i * 4;
    int dd[4] = {dv.x, dv.y, dv.z, dv.w};
    int ss[4] = {sv.x, sv.y, sv.z, sv.w};
    #pragma unroll
    for (int j = 0; j < 4; j++) {
      int d = dd[j], s = ss[j];
      float r = rowmax[s];
      unsigned mk = (__float_as_uint(r) >> 31);
      float av = fabsf(r);
      if (mk) hi = fmaxf(hi, av); else lo = fmaxf(lo, av);
      unsigned b = (unsigned)d >> bsh;
      unsigned pos = base[b] + atomicAdd(&h[b], 1u);
      if (full)
        cbuf64[pos] = ((unsigned long long)(((((unsigned)d) & lmask) << 24) | (unsigned)s) << 32)
                      | ((mk << 24) | (unsigned)(e0 + j));
      else
        cbuf32[pos] = ((((unsigned)d) & lmask) << 24) | (unsigned)(e0 + j);
    }
  }
  for (int e = cbase + n4 * 4 + threadIdx.x; e < cend; e += 256) {
    int d = dst[e], s = src[e];
    float r = rowmax[s];
    unsigned mk = (__float_as_uint(r) >> 31);
    float av = fabsf(r);
    if (mk) hi = fmaxf(hi, av); else lo = fmaxf(lo, av);
    unsigned b = (unsigned)d >> bsh;
    unsigned pos = base[b] + atomicAdd(&h[b], 1u);
    if (full)
      cbuf64[pos] = ((unsigned long long)(((((unsigned)d) & lmask) << 24) | (unsigned)s) << 32)
                    | ((mk << 24) | (unsigned)e);
    else
      cbuf32[pos] = ((((unsigned)d) & lmask) << 24) | (unsigned)e;
  }
  for (int o = 32; o; o >>= 1) { hi = fmaxf(hi, __shfl_xor(hi, o)); lo = fmaxf(lo, __shfl_xor(lo, o)); }
  int wid = threadIdx.x >> 6, lane = threadIdx.x & 63;
  if (lane == 0) { sh_hi[wid] = hi; sh_lo[wid] = lo; }
  __syncthreads();
  if (threadIdx.x == 0) {
    float hh = fmaxf(fmaxf(sh_hi[0], sh_hi[1]), fmaxf(sh_hi[2], sh_hi[3]));
    float ll = fmaxf(fmaxf(sh_lo[0], sh_lo[1]), fmaxf(sh_lo[2], sh_lo[3]));
    atomicMax(&slot_ehi[blockIdx.x & 255], __float_as_uint(hh));
    atomicMax(&slot_elo[blockIdx.x & 255], __float_as_uint(ll));
  }
}

// One block per coarse bucket: stage entries in LDS (single global read),
// per-node counts + scan, write cnt/start, scatter within bucket region.
// Also appends d>16 nodes to nodeB (one global atomicAdd per block).
__global__ void k_finesort(const unsigned long long* cbuf64, const unsigned* cbuf32,
                           const unsigned* cstart,
                           unsigned long long* opay, unsigned* order32,
                           unsigned* cnt, unsigned* start, unsigned* head,
                           unsigned* nodeB, int N, int bsh, int full) {
  __shared__ unsigned h[256], lofs[256], cur[256];
  __shared__ unsigned long long ent[FS_CAP];
  __shared__ unsigned bigcnt, bigbase;
  int b = blockIdx.x;
  unsigned rbase = cstart[b], rend = cstart[b + 1];
  unsigned n = rend - rbase;
  int t = threadIdx.x;
  h[t] = 0u;
  if (t == 0) bigcnt = 0u;
  __syncthreads();
  bool staged = (n <= (unsigned)FS_CAP);
  if (staged) {
    for (unsigned j = (unsigned)t; j < n; j += 256) {
      unsigned long long v = full ? cbuf64[rbase + j]
                                  : (unsigned long long)cbuf32[rbase + j];
      ent[j] = v;
      unsigned loc = full ? (unsigned)(v >> 56) : (((unsigned)v) >> 24);
      atomicAdd(&h[loc], 1u);
    }
  } else {
    for (unsigned j = rbase + (unsigned)t; j < rend; j += 256) {
      unsigned loc = full ? (unsigned)(cbuf64[j] >> 56) : (cbuf32[j] >> 24);
      atomicAdd(&h[loc], 1u);
    }
  }
  __syncthreads();
  lofs[t] = h[t];
  __syncthreads();
  for (int off = 1; off < 256; off <<= 1) {
    unsigned v = (t >= off) ? lofs[t - off] : 0u;
    __syncthreads();
    lofs[t] += v;
    __syncthreads();
  }
  unsigned dcount = h[t];
  unsigned excl = lofs[t] - dcount;
  cur[t] = excl;
  int nper = 1 << bsh;
  int node = (b << bsh) + t;
  bool valid = (t < nper) && (node < N);
  if (valid) { cnt[node] = dcount; start[node] = rbase + excl; }
  unsigned myidx = 0u;
  bool big = valid && dcount > 16u;
  if (big) myidx = atomicAdd(&bigcnt, 1u);
  __syncthreads();
  if (t == 0 && bigcnt) bigbase = atomicAdd(&head[11], bigcnt);
  __syncthreads();
  if (big) nodeB[bigbase + myidx] = (unsigned)node;
  if (staged) {
    for (unsigned j = (unsigned)t; j < n; j += 256) {
      unsigned long long v = ent[j];
      unsigned loc = full ? (unsigned)(v >> 56) : (((unsigned)v) >> 24);
      unsigned pos = rbase + atomicAdd(&cur[loc], 1u);
      if (full) opay[pos] = v; else order32[pos] = (unsigned)v & 0x00FFFFFFu;
    }
  } else {
    for (unsigned j = rbase + (unsigned)t; j < rend; j += 256) {
      if (full) {
        unsigned long long v = cbuf64[j];
        unsigned pos = rbase + atomicAdd(&cur[(unsigned)(v >> 56)], 1u);
        opay[pos] = v;
      } else {
        unsigned v = cbuf32[j];
        unsigned pos = rbase + atomicAdd(&cur[v >> 24], 1u);
        order32[pos] = v & 0x00FFFFFFu;
      }
    }
  }
  __syncthreads();
  if (valid && dcount > 64u) {  // practically never; correctness fallback
    unsigned s0 = rbase + excl;
    if (full) {
      for (unsigned i = 1; i < dcount; i++) {
        unsigned long long key = opay[s0 + i];
        unsigned kk = (unsigned)key & 0xFFFFFFu;
        int j = (int)i - 1;
        while (j >= 0 && ((unsigned)opay[s0 + j] & 0xFFFFFFu) > kk) {
          opay[s0 + j + 1] = opay[s0 + j]; j--;
        }
        opay[s0 + (unsigned)(j + 1)] = key;
      }
    } else {
      for (unsigned i = 1; i < dcount; i++) {
        unsigned key = order32[s0 + i];
        int j = (int)i - 1;
        while (j >= 0 && order32[s0 + j] > key) { order32[s0 + j + 1] = order32[s0 + j]; j--; }
        order32[s0 + (unsigned)(j + 1)] = key;
      }
    }
  }
}

// Reduce 256-slot amax arrays -> scales in head. which=0: msg; which=1: out.
__global__ void k_scales(unsigned* head, const unsigned* shi, const unsigned* slo, int which) {
  __shared__ unsigned smh[256], sml[256];
  int t = threadIdx.x;
  smh[t] = shi[t]; sml[t] = slo[t];
  __syncthreads();
  for (int off = 128; off > 0; off >>= 1) {
    if (t < off) {
      smh[t] = smh[t] > smh[t + off] ? smh[t] : smh[t + off];
      sml[t] = sml[t] > sml[t + off] ? sml[t] : sml[t + off];
    }
    __syncthreads();
  }
  if (t == 0) {
    float* hf = (float*)head;
    float ah = __uint_as_float(smh[0]);
    float al = __uint_as_float(sml[0]);
    hf[6 + which * 2]     = __fdiv_rn(fmaxf(ah, 1e-8f), 127.0f);
    hf[6 + which * 2 + 1] = __fdiv_rn(fmaxf(al, 1e-8f), 7.0f);
  }
}

// Quantize all rows to int8 codes (value = scale*(float)code, bit-exact).
__global__ void k_quant8(const float* x, signed char* xq8, const unsigned char* msk,
                         const unsigned* head, int N) {
  int w = (int)((blockIdx.x * blockDim.x + threadIdx.x) >> 6);
  int lane = threadIdx.x & 63;
  if (w >= N) return;
  const float* hf = (const float*)head;
  bool m = msk[w] != 0;
  float sc = m ? hf[6] : hf[7];
  float qm = m ? 127.0f : 7.0f;
  float t = __fdiv_rn(x[(size_t)w * 64 + lane], sc);
  t = fminf(fmaxf(t, -qm), qm);
  t = rintf(t);
  xq8[(size_t)w * 64 + lane] = (signed char)t;
}

// Final fake-quant of output rows (in-place, float).
__global__ void k_quant_rows(const float* in, float* out, const unsigned char* msk,
                             const unsigned* head, int N) {
  int w = (int)((blockIdx.x * blockDim.x + threadIdx.x) >> 6);
  int lane = threadIdx.x & 63;
  if (w >= N) return;
  const float* hf = (const float*)head;
  bool m = msk[w] != 0;
  float sc = m ? hf[8] : hf[9];
  float qm = m ? 127.0f : 7.0f;
  float v = in[(size_t)w * 64 + lane];
  float t = __fdiv_rn(v, sc);
  t = fminf(fmaxf(t, -qm), qm);
  t = rintf(t);
  out[(size_t)w * 64 + lane] = __fmul_rn(sc, t);
}

// Small nodes (d<=16), direct node indexing: 16-lane group per node, lane =
// 4 features, bitonic-16 order restore, 16 uniform u32 gathers in flight,
// single byte-decode path (no format divergence).
__global__ void k_aggr_small(const signed char* xq8,
                             const unsigned long long* opay, const unsigned* order32,
                             const int* src, const unsigned char* msk,
                             const unsigned* start, const unsigned* cnt,
                             const unsigned* head,
                             unsigned* slot_ohi, unsigned* slot_olo,
                             float* out, int N, int mode) {
  int t = blockIdx.x * blockDim.x + threadIdx.x;
  int node = t >> 4;
  int g = threadIdx.x & 15;
  if (node >= N) return;
  unsigned d = cnt[node];
  if (d > 16u) return;
  unsigned s0 = start[node];
  const float* hf = (const float*)head;
  float shi = hf[6], slo = hf[7];

  unsigned key = 0xFFFFFFFFu, pay = 0u;
  if ((unsigned)g < d) {
    if (mode == 2) {
      unsigned long long v = opay[s0 + (unsigned)g];
      key = (unsigned)v & 0xFFFFFFu;
      pay = ((unsigned)(v >> 32) & 0xFFFFFFu) | (((unsigned)(v >> 24) & 1u) << 31);
    } else {
      unsigned e = order32[s0 + (unsigned)g];
      int s = src[e];
      key = e;
      pay = (unsigned)s | (((unsigned)msk[s]) << 31);
    }
  }
  #pragma unroll
  for (int size = 2; size <= 16; size <<= 1) {
    #pragma unroll
    for (int stride = size >> 1; stride > 0; stride >>= 1) {
      unsigned ok = __shfl_xor(key, stride);
      unsigned op = __shfl_xor(pay, stride);
      bool up = ((g & size) == 0);
      bool keepMin = (((g & stride) == 0) == up);
      bool sw = keepMin ? (ok < key) : (ok > key);
      if (sw) { key = ok; pay = op; }
    }
  }
  int gbase = threadIdx.x & ~15;
  unsigned wv[16];
  #pragma unroll
  for (int j = 0; j < 16; j++) {
    int sl = gbase + ((j < (int)d) ? j : 0);
    unsigned p = __shfl(pay, sl);
    wv[j] = *(const unsigned*)(xq8 + (size_t)(p & 0x7FFFFFFFu) * 64 + g * 4);
  }
  float acc0 = 0.0f, acc1 = 0.0f, acc2 = 0.0f, acc3 = 0.0f;
  #pragma unroll
  for (int j = 0; j < 16; j++) {
    int sl = gbase + ((j < (int)d) ? j : 0);
    unsigned p = __shfl(pay, sl);
    float s = (j < (int)d) ? ((p >> 31) ? shi : slo) : 0.0f;  // 0-scale pads: +-0 adds
    unsigned w = wv[j];
    acc0 = __fadd_rn(acc0, __fmul_rn(s, (float)(int)(signed char)(w & 0xFF)));
    acc1 = __fadd_rn(acc1, __fmul_rn(s, (float)(int)(signed char)((w >> 8) & 0xFF)));
    acc2 = __fadd_rn(acc2, __fmul_rn(s, (float)(int)(signed char)((w >> 16) & 0xFF)));
    acc3 = __fadd_rn(acc3, __fmul_rn(s, (float)(int)(signed char)((w >> 24) & 0xFF)));
  }
  float4 o4; o4.x = acc0; o4.y = acc1; o4.z = acc2; o4.w = acc3;
  *(float4*)(out + (size_t)node * 64 + g * 4) = o4;

  float a = fmaxf(fmaxf(fabsf(acc0), fabsf(acc1)), fmaxf(fabsf(acc2), fabsf(acc3)));
  #pragma unroll
  for (int o = 8; o; o >>= 1) a = fmaxf(a, __shfl_xor(a, o));
  if (g == 0) {
    unsigned* sl = msk[node] ? slot_ohi : slot_olo;
    atomicMax(&sl[node & 255], __float_as_uint(a));
  }
}

// Wave-per-node path: big-node list (use_list=1) or all nodes (mode0).
__global__ void k_aggr_wave(const signed char* xq8, const float* x,
                            const unsigned long long* opay, const unsigned* order32,
                            const int* src, const unsigned char* msk,
                            const unsigned* start, const unsigned* cnt,
                            const unsigned* head, const unsigned* nodeB,
                            unsigned* slot_ohi, unsigned* slot_olo,
                            float* out, int N, int mode, int use_list) {
  int w = (int)((blockIdx.x * blockDim.x + threadIdx.x) >> 6);
  int lane = threadIdx.x & 63;
  int node;
  if (use_list) {
    unsigned nB = head[11];
    if ((unsigned)w >= nB) return;
    node = (int)nodeB[w];
  } else {
    if (w >= N) return;
    node = w;
  }
  unsigned d = cnt[node];
  unsigned s0 = start[node];
  const float* hf = (const float*)head;
  float shi = hf[6], slo = hf[7];
  float acc = 0.0f;

  if (d <= 64u) {
    unsigned key = 0xFFFFFFFFu, pay = 0u;
    if ((unsigned)lane < d) {
      if (mode == 2) {
        unsigned long long v = opay[s0 + (unsigned)lane];
        key = (unsigned)v & 0xFFFFFFu;
        pay = ((unsigned)(v >> 32) & 0xFFFFFFu) | (((unsigned)(v >> 24) & 1u) << 31);
      } else {
        unsigned e = order32[s0 + (unsigned)lane];
        int s = src[e];
        key = e;
        pay = (unsigned)s | (((unsigned)msk[s]) << 31);
      }
    }
    #pragma unroll
    for (int size = 2; size <= 32; size <<= 1) {
      #pragma unroll
      for (int stride = size >> 1; stride > 0; stride >>= 1) {
        unsigned ok = __shfl_xor(key, stride);
        unsigned op = __shfl_xor(pay, stride);
        bool up = ((lane & size) == 0);
        bool keepMin = (((lane & stride) == 0) == up);
        bool sw = keepMin ? (ok < key) : (ok > key);
        if (sw) { key = ok; pay = op; }
      }
    }
    if (d > 32u) {
      #pragma unroll
      for (int stride = 32; stride > 0; stride >>= 1) {
        unsigned ok = __shfl_xor(key, stride);
        unsigned op = __shfl_xor(pay, stride);
        bool keepMin = ((lane & stride) == 0);
        bool sw = keepMin ? (ok < key) : (ok > key);
        if (sw) { key = ok; pay = op; }
      }
    }
    for (unsigned kb = 0; kb < d; kb += 16) {
      float vv[16];
      #pragma unroll
      for (int j = 0; j < 16; j++) {
        unsigned kk = kb + (unsigned)j;
        int sl = (int)(kk < d ? kk : 0u);
        unsigned p = __shfl(pay, sl);
        float sc = (p >> 31) ? shi : slo;
        float scm = (kk < d) ? sc : 0.0f;
        unsigned sn = p & 0x7FFFFFFFu;
        float q;
        if (mode >= 1) {
          q = (float)xq8[(size_t)sn * 64 + lane];
        } else {
          float qm = (p >> 31) ? 127.0f : 7.0f;
          float tq = __fdiv_rn(x[(size_t)sn * 64 + lane], sc);
          tq = fminf(fmaxf(tq, -qm), qm);
          q = rintf(tq);
        }
        vv[j] = __fmul_rn(scm, q);
      }
      #pragma unroll
      for (int j = 0; j < 16; j++) acc = __fadd_rn(acc, vv[j]);
    }
  } else {
    for (unsigned k = 0; k < d; k++) {
      unsigned sn; bool m;
      if (mode == 2) {
        unsigned long long v = opay[s0 + k];
        sn = (unsigned)(v >> 32) & 0xFFFFFFu;
        m = ((v >> 24) & 1ull) != 0;
      } else {
        unsigned e = order32[s0 + k];
        sn = (unsigned)src[e];
        m = msk[sn] != 0;
      }
      float sc = m ? shi : slo;
      float q;
      if (mode >= 1) {
        q = (float)xq8[(size_t)sn * 64 + lane];
      } else {
        float qm = m ? 127.0f : 7.0f;
        float tq = __fdiv_rn(x[(size_t)sn * 64 + lane], sc);
        tq = fminf(fmaxf(tq, -qm), qm);
        q = rintf(tq);
      }
      acc = __fadd_rn(acc, __fmul_rn(sc, q));
    }
  }

  out[(size_t)node * 64 + lane] = acc;

  float a = fabsf(acc);
  for (int o = 32; o; o >>= 1) a = fmaxf(a, __shfl_xor(a, o));
  if (lane == 0) {
    unsigned* sl = (msk[node] != 0) ? slot_ohi : slot_olo;
    atomicMax(&sl[node & 255], __float_as_uint(a));
  }
}

extern "C" void kernel_launch(void* const* d_in, const int* in_sizes, int n_in,
                              void* d_out, int out_size, void* d_ws, size_t ws_size,
                              hipStream_t stream) {
  const float* x = (const float*)d_in[0];
  const int* ei = (const int*)d_in[1];
  const void* mraw = d_in[2];
  int N = in_sizes[2];
  int E = in_sizes[1] / 2;
  const int* src = ei;
  const int* dst = ei + E;
  float* out = (float*)d_out;

  int bsh = 7;
  while ((((N - 1) >> bsh) + 1) > 1024 && bsh < 8) bsh++;
  int NB = ((N - 1) >> bsh) + 1;
  int vec = (((uintptr_t)src & 15) == 0) && (((uintptr_t)dst & 15) == 0) && ((E & 3) == 0);

  char* ws = (char*)d_ws;
  auto al = [](size_t v) { return ((v + 255) / 256) * 256; };
  size_t o_sehi = 256, o_selo = 1280, o_sohi = 2304, o_solo = 3328;
  size_t o_ccnt = 4352;
  size_t o_cstart = al(o_ccnt + (size_t)(NB + 1) * 4);
  size_t o_bwrite = al(o_cstart + (size_t)(NB + 1) * 4);
  size_t o_msk = al(o_bwrite + (size_t)NB * 4);
  size_t o_rowmax = al(o_msk + (size_t)N);
  size_t o_cnt = o_rowmax + (size_t)N * 4;
  size_t o_start = o_cnt + (size_t)N * 4;
  size_t o_nodeB = o_start + (size_t)N * 4;
  size_t o_cbuf = al(o_nodeB + (size_t)N * 4);

  // FULL layout
  size_t o_opay = al(o_cbuf + (size_t)E * 8);
  size_t o_xq8f = al(o_opay + (size_t)E * 8);
  size_t need_full = o_xq8f + (size_t)N * 64;
  // COMPAT layout
  size_t o_order_c = al(o_cbuf + (size_t)E * 4);
  size_t o_xq8c = al(o_order_c + (size_t)E * 4);
  size_t need_compat = o_xq8c + (size_t)N * 64;

  int mode;
  if (ws_size >= need_full && E < (1 << 24) && N < (1 << 24)) mode = 2;
  else if (ws_size >= need_compat && E < (1 << 24)) mode = 1;
  else mode = 0;

  unsigned* head = (unsigned*)ws;
  unsigned* slot_ehi = (unsigned*)(ws + o_sehi);
  unsigned* slot_elo = (unsigned*)(ws + o_selo);
  unsigned* slot_ohi = (unsigned*)(ws + o_sohi);
  unsigned* slot_olo = (unsigned*)(ws + o_solo);
  unsigned* ccnt = (unsigned*)(ws + o_ccnt);
  unsigned* cstart = (unsigned*)(ws + o_cstart);
  unsigned* bwrite = (unsigned*)(ws + o_bwrite);
  unsigned char* msk = (unsigned char*)(ws + o_msk);
  float* rowmax = (float*)(ws + o_rowmax);
  unsigned* cnt = (unsigned*)(ws + o_cnt);
  unsigned* start = (unsigned*)(ws + o_start);
  unsigned* nodeB = (unsigned*)(ws + o_nodeB);
  unsigned long long* cbuf64 = (unsigned long long*)(ws + o_cbuf);
  unsigned* cbuf32 = (unsigned*)(ws + o_cbuf);
  unsigned long long* opay = (unsigned long long*)(ws + o_opay);
  unsigned* order32 = (unsigned*)(ws + o_order_c);
  signed char* xq8 = (signed char*)(ws + ((mode == 2) ? o_xq8f : o_xq8c));

  int rowBlocks = (N + 3) / 4;
  int nbp = (E + BP_CHUNK - 1) / BP_CHUNK;
  int full = (mode == 2);

  k_zero<<<8, 256, 0, stream>>>(head, (int)(o_cstart / 4));
  k_detect<<<256, 256, 0, stream>>>((const unsigned char*)mraw, head, N);
  k_rowmax_canon<<<rowBlocks, 256, 0, stream>>>(x, mraw, head, rowmax, msk, N);
  k_edge_hist<<<256, 256, 0, stream>>>(dst, ccnt, E, NB, bsh, vec);
  k_cscan<<<1, 256, 0, stream>>>(ccnt, cstart, bwrite, NB);
  k_binplace<<<nbp, 256, 0, stream>>>(src, dst, rowmax, bwrite, cbuf64, cbuf32,
                                      slot_ehi, slot_elo, E, NB, bsh, full, vec);
  k_scales<<<1, 256, 0, stream>>>(head, slot_ehi, slot_elo, 0);
  if (mode >= 1)
    k_quant8<<<rowBlocks, 256, 0, stream>>>(x, xq8, msk, head, N);
  k_finesort<<<NB, 256, 0, stream>>>(cbuf64, cbuf32, cstart, opay, order32,
                                     cnt, start, head, nodeB, N, bsh, full);
  if (mode >= 1) {
    k_aggr_small<<<(N + 15) / 16, 256, 0, stream>>>(xq8, opay, order32, src, msk,
                                                    start, cnt, head,
                                                    slot_ohi, slot_olo, out, N, mode);
    k_aggr_wave<<<rowBlocks, 256, 0, stream>>>(xq8, x, opay, order32, src, msk,
                                               start, cnt, head, nodeB,
                                               slot_ohi, slot_olo, out, N, mode, 1);
  } else {
    k_aggr_wave<<<rowBlocks, 256, 0, stream>>>(xq8, x, opay, order32, src, msk,
                                               start, cnt, head, nodeB,
                                               slot_ohi, slot_olo, out, N, mode, 0);
  }
  k_scales<<<1, 256, 0, stream>>>(head, slot_ohi, slot_olo, 1);
  k_quant_rows<<<rowBlocks, 256, 0, stream>>>(out, out, msk, head, N);
}